// Round 18
// baseline (408.681 us; speedup 1.0000x reference)
//
#include <hip/hip_runtime.h>

typedef float f32x4 __attribute__((ext_vector_type(4)));
typedef short short8 __attribute__((ext_vector_type(8)));

#define T_LEN 2048
#define HD 256
#define SD 64
#define DIN 768
#define DOUT 768
#define NCHUNK 32
#define CLEN 64

#define SBAR() __builtin_amdgcn_sched_barrier(0)

__device__ __forceinline__ unsigned short f2bf(float f) {
    unsigned int u = __float_as_uint(f);
    unsigned int r = u + 0x7FFFu + ((u >> 16) & 1u);
    return (unsigned short)(r >> 16);
}
__device__ __forceinline__ float bf2f(unsigned short h) {
    return __uint_as_float(((unsigned int)h) << 16);
}
__device__ __forceinline__ int swz(int row, int col, int stride) {
    return row * stride + (col ^ ((row & 7) << 3));
}
#define GLL(gp, lp) __builtin_amdgcn_global_load_lds( \
    (const __attribute__((address_space(1))) void*)(gp), \
    (__attribute__((address_space(3))) void*)(lp), 16, 0, 0)

// ---------------- weight conversion ----------------
__global__ __launch_bounds__(256) void cvt_w_k(const float* __restrict__ s0, const float* __restrict__ s1,
                                               const float* __restrict__ s2, const float* __restrict__ s3,
                                               const float* __restrict__ s4, const float* __restrict__ s5,
                                               unsigned short* __restrict__ d) {
    int i = blockIdx.x * 256 + threadIdx.x;
    if (i >= 1048576) return;
    float v;
    if (i < 196608)      v = s0[i];
    else if (i < 262144) v = s1[i - 196608];
    else if (i < 524288) v = s2[i - 262144];
    else if (i < 786432) v = s3[i - 524288];
    else if (i < 851968) v = s4[i - 786432];
    else                 v = s5[i - 851968];
    d[i] = f2bf(v);
}

// ---------------- A^64 via bf16-split MFMA (6 squarings, verified) ----------------
__global__ __launch_bounds__(256) void matpow_k(const float* __restrict__ A, float* __restrict__ Apow) {
    __shared__ unsigned short Mh[4096], Ml[4096], MhT[4096], MlT[4096];
    const int l = blockIdx.x, tid = threadIdx.x;
    const int w = tid >> 6, ln = tid & 63, ll = ln & 15, lh = ln >> 4;
    const float* src = A + l * 4096;
    for (int i = tid; i < 4096; i += 256) {
        float v = src[i];
        unsigned short hi = f2bf(v);
        unsigned short lo = f2bf(v - bf2f(hi));
        int r = i >> 6, c = i & 63;
        Mh[swz(r, c, 64)] = hi;  Ml[swz(r, c, 64)] = lo;
        MhT[swz(c, r, 64)] = hi; MlT[swz(c, r, 64)] = lo;
    }
    __syncthreads();
    for (int it = 0; it < 6; it++) {
        f32x4 acc[4] = {};
#pragma unroll
        for (int ks = 0; ks < 2; ks++) {
            int ar = w * 16 + ll, c0 = ks * 32 + lh * 8;
            short8 ah = *reinterpret_cast<const short8*>(&Mh[swz(ar, c0, 64)]);
            short8 al = *reinterpret_cast<const short8*>(&Ml[swz(ar, c0, 64)]);
#pragma unroll
            for (int nf = 0; nf < 4; nf++) {
                int br = nf * 16 + ll;
                short8 bh = *reinterpret_cast<const short8*>(&MhT[swz(br, c0, 64)]);
                short8 bl = *reinterpret_cast<const short8*>(&MlT[swz(br, c0, 64)]);
                acc[nf] = __builtin_amdgcn_mfma_f32_16x16x32_bf16(ah, bh, acc[nf], 0, 0, 0);
                acc[nf] = __builtin_amdgcn_mfma_f32_16x16x32_bf16(ah, bl, acc[nf], 0, 0, 0);
                acc[nf] = __builtin_amdgcn_mfma_f32_16x16x32_bf16(al, bh, acc[nf], 0, 0, 0);
            }
        }
        __syncthreads();
#pragma unroll
        for (int nf = 0; nf < 4; nf++)
#pragma unroll
            for (int r = 0; r < 4; r++) {
                float v = acc[nf][r];
                int row = w * 16 + lh * 4 + r, col = nf * 16 + ll;
                unsigned short hi = f2bf(v);
                unsigned short lo = f2bf(v - bf2f(hi));
                Mh[swz(row, col, 64)] = hi;  Ml[swz(row, col, 64)] = lo;
                MhT[swz(col, row, 64)] = hi; MlT[swz(col, row, 64)] = lo;
            }
        __syncthreads();
    }
    for (int i = tid; i < 4096; i += 256) {
        int r = i >> 6, c = i & 63;
        Apow[l * 4096 + i] = bf2f(Mh[swz(r, c, 64)]) + bf2f(Ml[swz(r, c, 64)]);
    }
}

// ---------------- fused in-proj + LN, BM=32, W staged via GLL with bank swizzle ----------------
// LDS tile [256][32] bf16; 16B slot-swizzle: content(row, s) = global(row, s ^ ((row>>1)&3))
__global__ __launch_bounds__(256) void in_ln_k(const float* __restrict__ x,
                                               const unsigned short* __restrict__ w_in,
                                               const float* __restrict__ inb,
                                               const float* __restrict__ lng, const float* __restrict__ lnb,
                                               unsigned short* __restrict__ hb, unsigned short* __restrict__ xnb) {
    __shared__ unsigned short smem[8192 + 32 * 264];   // Ws 16KB + hnb 16.9KB
    unsigned short* Ws = smem;
    unsigned short* hnb = smem + 8192;
    const int tid = threadIdx.x, l = tid & 63, w = tid >> 6;
    const int ll = l & 15, lh = l >> 4;
    const int mf = w >> 1, nh = w & 1;
    const int m0 = blockIdx.x * 32;
    const float* ap = x + (size_t)(m0 + mf * 16 + ll) * DIN + lh * 8;
    // pre-swizzled global source: chunk (l&3) ^ ((l>>3)&3)
    const unsigned short* gwb = w_in + (size_t)(w * 64 + (l >> 2)) * DIN + (((l & 3) ^ ((l >> 3) & 3)) * 8);
    unsigned short* lwb = &Ws[(w * 64) * 32];
    f32x4 acc[8] = {};
    const int rsw = (ll >> 1) & 3;   // read-slot xor for rows base16 + ll
    for (int k0 = 0; k0 < DIN; k0 += 32) {
#pragma unroll
        for (int q = 0; q < 4; q++)
            GLL(gwb + (size_t)(q * 16) * DIN + k0, lwb + q * 16 * 32);
        float4 a0 = *reinterpret_cast<const float4*>(ap + k0);
        float4 a1 = *reinterpret_cast<const float4*>(ap + k0 + 4);
        short8 af;
        af[0] = (short)f2bf(a0.x); af[1] = (short)f2bf(a0.y);
        af[2] = (short)f2bf(a0.z); af[3] = (short)f2bf(a0.w);
        af[4] = (short)f2bf(a1.x); af[5] = (short)f2bf(a1.y);
        af[6] = (short)f2bf(a1.z); af[7] = (short)f2bf(a1.w);
        __syncthreads();
#pragma unroll
        for (int j = 0; j < 8; j++) {
            short8 b = *reinterpret_cast<const short8*>(&Ws[(size_t)(nh * 128 + j * 16 + ll) * 32 + ((lh ^ rsw) * 8)]);
            acc[j] = __builtin_amdgcn_mfma_f32_16x16x32_bf16(af, b, acc[j], 0, 0, 0);
        }
        __syncthreads();
    }
#pragma unroll
    for (int j = 0; j < 8; j++)
#pragma unroll
        for (int r = 0; r < 4; r++) {
            int rowl = mf * 16 + lh * 4 + r;
            int col = nh * 128 + j * 16 + ll;
            hnb[rowl * 264 + col] = f2bf(acc[j][r] + inb[col]);
        }
    __syncthreads();
#pragma unroll
    for (int q = 0; q < 8; q++) {
        int rowl = w * 8 + q;
        size_t gidx = (size_t)(m0 + rowl) * HD + l * 4;
        ushort4 hv = *reinterpret_cast<const ushort4*>(&hnb[rowl * 264 + l * 4]);
        float o0 = bf2f(hv.x), o1 = bf2f(hv.y), o2 = bf2f(hv.z), o3 = bf2f(hv.w);
        float s = o0 + o1 + o2 + o3;
        float s2 = o0 * o0 + o1 * o1 + o2 * o2 + o3 * o3;
#pragma unroll
        for (int mm = 1; mm < 64; mm <<= 1) { s += __shfl_xor(s, mm); s2 += __shfl_xor(s2, mm); }
        float mean = s * (1.f / 256.f);
        float var = s2 * (1.f / 256.f) - mean * mean;
        float rstd = rsqrtf(var + 1e-5f);
        int c = l * 4;
        *reinterpret_cast<ushort4*>(hb + gidx) = hv;
        ushort4 xo;
        xo.x = f2bf((o0 - mean) * rstd * lng[c + 0] + lnb[c + 0]);
        xo.y = f2bf((o1 - mean) * rstd * lng[c + 1] + lnb[c + 1]);
        xo.z = f2bf((o2 - mean) * rstd * lng[c + 2] + lnb[c + 2]);
        xo.w = f2bf((o3 - mean) * rstd * lng[c + 3] + lnb[c + 3]);
        *reinterpret_cast<ushort4*>(xnb + gidx) = xo;
    }
}

// ---------------- m97-style staged GEMM core (K=256), bank-swizzled tiles ----------------
__device__ __forceinline__ void staged_core256(const unsigned short* __restrict__ A, int m0b,
                                               const unsigned short* __restrict__ W, int n0,
                                               unsigned short* As, unsigned short* Bs,
                                               int tid, f32x4 (*acc)[4]) {
    const int l = tid & 63, w = tid >> 6;
    const int ll = l & 15, lh = l >> 4;
    const int lr = l >> 2;
    const int lc = (((l & 3) ^ ((l >> 3) & 3)) * 8);   // pre-swizzled source chunk
    const unsigned short* ga1 = A + (size_t)(m0b + w * 32 + lr) * 256 + lc;
    const unsigned short* ga2 = ga1 + 16 * 256;
    const unsigned short* gb  = W + (size_t)(n0 + w * 16 + lr) * 256 + lc;
    unsigned short* la1 = As + w * 1024;
    unsigned short* la2 = As + w * 1024 + 512;
    unsigned short* lb  = Bs + w * 512;
    const int rs = ((ll >> 1) & 3);                     // read-slot xor
    const int rofs = ((lh ^ rs) * 8);
#pragma unroll
    for (int k0 = 0; k0 < 256; k0 += 32) {
        GLL(ga1 + k0, la1);
        GLL(ga2 + k0, la2);
        GLL(gb + k0, lb);
        __syncthreads();
        short8 a0 = *reinterpret_cast<const short8*>(&As[(w * 32 + ll) * 32 + rofs]);
        short8 a1 = *reinterpret_cast<const short8*>(&As[(w * 32 + 16 + ll) * 32 + rofs]);
        short8 b0 = *reinterpret_cast<const short8*>(&Bs[(ll) * 32 + rofs]);
        short8 b1 = *reinterpret_cast<const short8*>(&Bs[(16 + ll) * 32 + rofs]);
        short8 b2 = *reinterpret_cast<const short8*>(&Bs[(32 + ll) * 32 + rofs]);
        short8 b3 = *reinterpret_cast<const short8*>(&Bs[(48 + ll) * 32 + rofs]);
        acc[0][0] = __builtin_amdgcn_mfma_f32_16x16x32_bf16(a0, b0, acc[0][0], 0, 0, 0);
        acc[0][1] = __builtin_amdgcn_mfma_f32_16x16x32_bf16(a0, b1, acc[0][1], 0, 0, 0);
        acc[0][2] = __builtin_amdgcn_mfma_f32_16x16x32_bf16(a0, b2, acc[0][2], 0, 0, 0);
        acc[0][3] = __builtin_amdgcn_mfma_f32_16x16x32_bf16(a0, b3, acc[0][3], 0, 0, 0);
        acc[1][0] = __builtin_amdgcn_mfma_f32_16x16x32_bf16(a1, b0, acc[1][0], 0, 0, 0);
        acc[1][1] = __builtin_amdgcn_mfma_f32_16x16x32_bf16(a1, b1, acc[1][1], 0, 0, 0);
        acc[1][2] = __builtin_amdgcn_mfma_f32_16x16x32_bf16(a1, b2, acc[1][2], 0, 0, 0);
        acc[1][3] = __builtin_amdgcn_mfma_f32_16x16x32_bf16(a1, b3, acc[1][3], 0, 0, 0);
        __syncthreads();
    }
}

// ---------------- final GEMM, staged, fp32 out, nontemporal stores ----------------
template <int N>
__global__ __launch_bounds__(256) void gemm_k(const unsigned short* __restrict__ A,
                                              const unsigned short* __restrict__ W,
                                              const float* __restrict__ bias,
                                              float* __restrict__ outf) {
    __shared__ char smem[128 * 68 * 4];
    unsigned short* As = (unsigned short*)smem;
    unsigned short* Bs = As + 4096;
    float* sf = (float*)smem;
    const int tid = threadIdx.x, l = tid & 63, w = tid >> 6;
    const int ll = l & 15, lh = l >> 4;
    const int m0b = blockIdx.x * 128;
    const int n0 = blockIdx.y * 64;
    f32x4 acc[2][4] = {};
    staged_core256(A, m0b, W, n0, As, Bs, tid, acc);
#pragma unroll
    for (int mf = 0; mf < 2; mf++)
#pragma unroll
        for (int nf = 0; nf < 4; nf++)
#pragma unroll
            for (int r = 0; r < 4; r++) {
                int rowl = w * 32 + mf * 16 + lh * 4 + r;
                int col = nf * 16 + ll;
                sf[rowl * 68 + col] = acc[mf][nf][r] + bias[n0 + col];
            }
    __syncthreads();
#pragma unroll
    for (int p = 0; p < 8; p++) {
        int rowl = p * 16 + (tid >> 4);
        int col = (tid & 15) * 4;
        f32x4 v = *reinterpret_cast<const f32x4*>(&sf[rowl * 68 + col]);
        __builtin_nontemporal_store(v, reinterpret_cast<f32x4*>(outf + (size_t)(m0b + rowl) * N + n0 + col));
    }
}

// ---------------- fused gate + ip GEMM, staged, BM=128 (grid y: 0..3 gate, 4 = ip) ----------------
__global__ __launch_bounds__(256) void gateip_k(const unsigned short* __restrict__ xnb,
                                                const unsigned short* __restrict__ wg,
                                                const unsigned short* __restrict__ wip,
                                                const float* __restrict__ gbias, const float* __restrict__ ipb,
                                                const float* __restrict__ Bv, const float* __restrict__ bA,
                                                unsigned short* __restrict__ gB, float* __restrict__ u) {
    __shared__ char smem[128 * 68 * 4];
    unsigned short* As = (unsigned short*)smem;
    unsigned short* Bs = As + 4096;
    float* sf = (float*)smem;
    unsigned short* su = (unsigned short*)smem;
    const int tid = threadIdx.x, l = tid & 63, w = tid >> 6;
    const int ll = l & 15, lh = l >> 4;
    const int m0b = blockIdx.x * 128;
    const int y = blockIdx.y;
    const bool gate = (y < 4);
    const int n0 = gate ? y * 64 : 0;
    f32x4 acc[2][4] = {};
    staged_core256(xnb, m0b, gate ? wg : wip, n0, As, Bs, tid, acc);
    if (gate) {
#pragma unroll
        for (int mf = 0; mf < 2; mf++)
#pragma unroll
            for (int nf = 0; nf < 4; nf++)
#pragma unroll
                for (int r = 0; r < 4; r++) {
                    int rowl = w * 32 + mf * 16 + lh * 4 + r;
                    int col = nf * 16 + ll;
                    float v = acc[mf][nf][r] + gbias[n0 + col];
                    su[rowl * 72 + col] = f2bf(1.f / (1.f + __expf(-v)));
                }
        __syncthreads();
#pragma unroll
        for (int p = 0; p < 8; p++) {
            int rowl = p * 16 + (tid >> 4);
            int col = (tid & 15) * 4;
            ushort4 v = *reinterpret_cast<const ushort4*>(&su[rowl * 72 + col]);
            *reinterpret_cast<ushort4*>(gB + (size_t)(m0b + rowl) * HD + n0 + col) = v;
        }
    } else {
#pragma unroll
        for (int mf = 0; mf < 2; mf++)
#pragma unroll
            for (int nf = 0; nf < 4; nf++)
#pragma unroll
                for (int r = 0; r < 4; r++) {
                    int rowl = w * 32 + mf * 16 + lh * 4 + r;
                    int col = nf * 16 + ll;
                    float v = acc[mf][nf][r] + ipb[col];
                    sf[rowl * 68 + col] = Bv[col] * v + bA[col];
                }
        __syncthreads();
#pragma unroll
        for (int p = 0; p < 8; p++) {
            int rowl = p * 16 + (tid >> 4);
            int col = (tid & 15) * 4;
            int m = m0b + rowl;           // bt-order
            int t = m & 2047, b2 = m >> 11;
            float4 v = *reinterpret_cast<const float4*>(&sf[rowl * 68 + col]);
            *reinterpret_cast<float4*>(u + ((size_t)((t << 3) + b2)) * 64 + col) = v;
        }
    }
}

// ---------------- fused Cm + proj + blend + LN(next layer); bf16 residual ----------------
template <bool LAST>
__global__ __launch_bounds__(256) void post3_k(const unsigned short* __restrict__ Hs,
                                               const unsigned short* __restrict__ wc,
                                               const float* __restrict__ bC,
                                               const unsigned short* __restrict__ wp,
                                               const float* __restrict__ pb,
                                               const unsigned short* __restrict__ gB,
                                               unsigned short* __restrict__ xnb,
                                               unsigned short* __restrict__ hb,
                                               const float* __restrict__ lng2, const float* __restrict__ lnb2) {
    __shared__ unsigned short ys[32 * 256];
    __shared__ unsigned short hnb[32 * 264];
    const int tid = threadIdx.x, l = tid & 63, w = tid >> 6;
    const int ll = l & 15, lh = l >> 4;
    const int mf = w >> 1, nh = w & 1;
    const int m0 = blockIdx.x * 32;          // tb-order
    {
        short8 ha[2], cb[8][2];
        const unsigned short* Ap = Hs + (size_t)(m0 + mf * 16 + ll) * SD + lh * 8;
#pragma unroll
        for (int ks = 0; ks < 2; ks++)
            ha[ks] = *reinterpret_cast<const short8*>(Ap + ks * 32);
#pragma unroll
        for (int ks = 0; ks < 2; ks++)
#pragma unroll
            for (int j = 0; j < 8; j++)
                cb[j][ks] = *reinterpret_cast<const short8*>(wc + (size_t)((nh * 8 + j) * 16 + ll) * SD + ks * 32 + lh * 8);
        SBAR();
        f32x4 acc[8] = {};
#pragma unroll
        for (int ks = 0; ks < 2; ks++)
#pragma unroll
            for (int j = 0; j < 8; j++)
                acc[j] = __builtin_amdgcn_mfma_f32_16x16x32_bf16(ha[ks], cb[j][ks], acc[j], 0, 0, 0);
#pragma unroll
        for (int j = 0; j < 8; j++)
#pragma unroll
            for (int r = 0; r < 4; r++) {
                int rowl = mf * 16 + lh * 4 + r;
                int col = (nh * 8 + j) * 16 + ll;
                ys[swz(rowl, col, 256)] = f2bf(acc[j][r] + bC[col]);
            }
    }
    __syncthreads();
    {
        f32x4 acc2[8] = {};
        const int arow = mf * 16 + ll;
#pragma unroll
        for (int kb = 0; kb < 4; kb++) {
            short8 pwf[8][2];
#pragma unroll
            for (int ks = 0; ks < 2; ks++)
#pragma unroll
                for (int j = 0; j < 8; j++)
                    pwf[j][ks] = *reinterpret_cast<const short8*>(wp + (size_t)((nh * 8 + j) * 16 + ll) * HD + kb * 64 + ks * 32 + lh * 8);
            SBAR();
#pragma unroll
            for (int ks = 0; ks < 2; ks++) {
                int c0 = kb * 64 + ks * 32 + lh * 8;
                short8 a = *reinterpret_cast<const short8*>(&ys[swz(arow, c0, 256)]);
#pragma unroll
                for (int j = 0; j < 8; j++)
                    acc2[j] = __builtin_amdgcn_mfma_f32_16x16x32_bf16(a, pwf[j][ks], acc2[j], 0, 0, 0);
            }
        }
#pragma unroll
        for (int j = 0; j < 8; j++)
#pragma unroll
            for (int r = 0; r < 4; r++) {
                int rowl = mf * 16 + lh * 4 + r;
                int col = (nh * 8 + j) * 16 + ll;
                hnb[rowl * 264 + col] = f2bf(acc2[j][r] + pb[col]);
            }
    }
    __syncthreads();
#pragma unroll
    for (int q = 0; q < 8; q++) {
        int rowl = w * 8 + q;
        int m = m0 + rowl;               // tb-order
        int t = m >> 3, b2 = m & 7;
        size_t gidx = ((size_t)((b2 << 11) + t)) * HD + l * 4;
        ushort4 hv = *reinterpret_cast<const ushort4*>(hb + gidx);
        ushort4 gv = *reinterpret_cast<const ushort4*>(gB + gidx);
        ushort4 xv = *reinterpret_cast<const ushort4*>(xnb + gidx);
        ushort4 yv = *reinterpret_cast<const ushort4*>(&hnb[rowl * 264 + l * 4]);
        float g0 = bf2f(gv.x), g1 = bf2f(gv.y), g2 = bf2f(gv.z), g3 = bf2f(gv.w);
        float o0 = bf2f(hv.x) + g0 * bf2f(yv.x) + (1.f - g0) * bf2f(xv.x);
        float o1 = bf2f(hv.y) + g1 * bf2f(yv.y) + (1.f - g1) * bf2f(xv.y);
        float o2 = bf2f(hv.z) + g2 * bf2f(yv.z) + (1.f - g2) * bf2f(xv.z);
        float o3 = bf2f(hv.w) + g3 * bf2f(yv.w) + (1.f - g3) * bf2f(xv.w);
        ushort4 hbv;
        hbv.x = f2bf(o0); hbv.y = f2bf(o1); hbv.z = f2bf(o2); hbv.w = f2bf(o3);
        *reinterpret_cast<ushort4*>(hb + gidx) = hbv;
        if constexpr (!LAST) {
            float s = o0 + o1 + o2 + o3;
            float s2 = o0 * o0 + o1 * o1 + o2 * o2 + o3 * o3;
#pragma unroll
            for (int mm = 1; mm < 64; mm <<= 1) { s += __shfl_xor(s, mm); s2 += __shfl_xor(s2, mm); }
            float mean = s * (1.f / 256.f);
            float var = s2 * (1.f / 256.f) - mean * mean;
            float rstd = rsqrtf(var + 1e-5f);
            int c = l * 4;
            ushort4 xo;
            xo.x = f2bf((o0 - mean) * rstd * lng2[c + 0] + lnb2[c + 0]);
            xo.y = f2bf((o1 - mean) * rstd * lng2[c + 1] + lnb2[c + 1]);
            xo.z = f2bf((o2 - mean) * rstd * lng2[c + 2] + lnb2[c + 2]);
            xo.w = f2bf((o3 - mean) * rstd * lng2[c + 3] + lnb2[c + 3]);
            *reinterpret_cast<ushort4*>(xnb + gidx) = xo;
        }
    }
}

// ---------------- scan helpers ----------------
__device__ __forceinline__ void loadA64(const float* __restrict__ Af, int s, float* a) {
#pragma unroll
    for (int q = 0; q < 16; q++) {
        float4 v = reinterpret_cast<const float4*>(Af + s * 64)[q];
        a[q * 4 + 0] = v.x; a[q * 4 + 1] = v.y; a[q * 4 + 2] = v.z; a[q * 4 + 3] = v.w;
    }
}

__device__ __forceinline__ float step64(const float* a, float h, float uu) {
    float ac0 = uu, ac1 = 0.f, ac2 = 0.f, ac3 = 0.f;
#pragma unroll
    for (int k = 0; k < 64; k += 4) {
        float b0 = __int_as_float(__builtin_amdgcn_readlane(__float_as_int(h), k + 0));
        float b1 = __int_as_float(__builtin_amdgcn_readlane(__float_as_int(h), k + 1));
        float b2 = __int_as_float(__builtin_amdgcn_readlane(__float_as_int(h), k + 2));
        float b3 = __int_as_float(__builtin_amdgcn_readlane(__float_as_int(h), k + 3));
        ac0 = fmaf(b0, a[k + 0], ac0);
        ac1 = fmaf(b1, a[k + 1], ac1);
        ac2 = fmaf(b2, a[k + 2], ac2);
        ac3 = fmaf(b3, a[k + 3], ac3);
    }
    return (ac0 + ac1) + (ac2 + ac3);
}

__global__ __launch_bounds__(64) void scan_chunk_k(const float* __restrict__ Af,
                                                   const float* __restrict__ u,
                                                   float* __restrict__ Slast) {
    const int c = blockIdx.x >> 3, b = blockIdx.x & 7;
    const int s = threadIdx.x;
    float a[64];
    loadA64(Af, s, a);
    const float* up = u + (c * CLEN) * 512 + b * 64 + s;
    float uv[CLEN];
#pragma unroll
    for (int i = 0; i < CLEN; i++) uv[i] = up[i * 512];
    float h = 0.f;
#pragma unroll
    for (int i = 0; i < CLEN; i++) h = step64(a, h, uv[i]);
    Slast[blockIdx.x * 64 + s] = h;
}

__global__ __launch_bounds__(64) void replay_k(const float* __restrict__ Af,
                                               const float* __restrict__ Apow,
                                               const float* __restrict__ u,
                                               const float* __restrict__ Slast,
                                               unsigned short* __restrict__ Hs,
                                               int* __restrict__ flag) {
    const int c = blockIdx.x >> 3, b = blockIdx.x & 7;
    const int s = threadIdx.x;
    float a[64];
    float carry = 0.f;
    if (c > 0) {
        loadA64(Apow, s, a);
        for (int j = 0; j < c; j++) {
            float sl = Slast[(j * 8 + b) * 64 + s];
            carry = step64(a, carry, sl);
        }
    }
    loadA64(Af, s, a);
    const float* up = u + (c * CLEN) * 512 + b * 64 + s;
    float uv[CLEN];
#pragma unroll
    for (int i = 0; i < CLEN; i++) uv[i] = up[i * 512];
    float h = carry;
    unsigned short* hp = Hs + (c * CLEN) * 512 + b * 64 + s;
    bool bad = false;
#pragma unroll
    for (int i = 0; i < CLEN; i++) {
        h = step64(a, h, uv[i]);
        bad |= (fabsf(h) > 10.f);
        hp[i * 512] = f2bf(h);
    }
    if (__any(bad ? 1 : 0)) {
        if (s == 0) atomicOr(flag, 1);
    }
}

__global__ __launch_bounds__(64) void scan_seq_k(const float* __restrict__ Af,
                                                 const float* __restrict__ u,
                                                 unsigned short* __restrict__ Hs,
                                                 const int* __restrict__ flag) {
    if (*flag == 0) return;
    const int b = blockIdx.x;
    const int s = threadIdx.x;
    float a[64];
    loadA64(Af, s, a);
    float h = 0.f;
    for (int t = 0; t < T_LEN; t++) {
        float uu = u[((t << 3) + b) * 64 + s];
        float hp = step64(a, h, uu);
        h = fminf(fmaxf(hp, -10.f), 10.f);
        Hs[((t << 3) + b) * 64 + s] = f2bf(h);
    }
}

// ---------------- launch ----------------
extern "C" void kernel_launch(void* const* d_in, const int* in_sizes, int n_in,
                              void* d_out, int out_size, void* d_ws, size_t ws_size,
                              hipStream_t stream) {
    const float* x    = (const float*)d_in[0];
    const float* inw  = (const float*)d_in[1];
    const float* inb  = (const float*)d_in[2];
    const float* lng  = (const float*)d_in[3];
    const float* lnb  = (const float*)d_in[4];
    const float* ipw  = (const float*)d_in[5];
    const float* ipb  = (const float*)d_in[6];
    const float* Amat = (const float*)d_in[7];
    const float* Bv   = (const float*)d_in[8];
    const float* Cm   = (const float*)d_in[9];
    const float* bA   = (const float*)d_in[10];
    const float* bC   = (const float*)d_in[11];
    const float* gw   = (const float*)d_in[12];
    const float* gbia = (const float*)d_in[13];
    const float* pw   = (const float*)d_in[14];
    const float* pb   = (const float*)d_in[15];
    const float* ow   = (const float*)d_in[16];
    const float* ob   = (const float*)d_in[17];

    char* ws = (char*)d_ws;
    float*          u  = (float*)(ws + 0);                   // 4 MB
    unsigned short* Hs = (unsigned short*)(ws + 4194304);    // 2 MB
    unsigned short* hb = (unsigned short*)(ws + 14680064);   // 8 MB (bf16 residual)
    unsigned short* wb = (unsigned short*)(ws + 25165824);   // 2 MB
    unsigned short* xnb = (unsigned short*)(ws + 44040192);  // 8 MB
    unsigned short* gB  = (unsigned short*)(ws + 52428800);  // 8 MB

    char* sc = (char*)d_out;   // small scratch; fully overwritten by final GEMM
    float* Apow  = (float*)(sc + 0);          // 64 KB: [4][64][64] (A^64)
    float* Slast = (float*)(sc + 65536);      // 64 KB
    int*   flag  = (int*)(sc + 196608);       // 16 B

    const unsigned short* w_in = wb + 0;
    const unsigned short* w_ip = wb + 196608;
    const unsigned short* w_g  = wb + 262144;
    const unsigned short* w_p  = wb + 524288;
    const unsigned short* w_c  = wb + 786432;
    const unsigned short* w_o  = wb + 851968;

    hipMemsetAsync(flag, 0, 16, stream);
    cvt_w_k<<<4096, 256, 0, stream>>>(inw, ipw, gw, pw, Cm, ow, wb);
    matpow_k<<<4, 256, 0, stream>>>(Amat, Apow);

    in_ln_k<<<512, 256, 0, stream>>>(x, w_in, inb, lng, lnb, hb, xnb);
    for (int i = 0; i < 4; i++) {
        gateip_k<<<dim3(128, 5), 256, 0, stream>>>(xnb, w_g + i * 65536, w_ip + i * 16384,
                                                   gbia + i * HD, ipb + i * SD,
                                                   Bv + i * SD, bA + i * SD, gB, u);
        scan_chunk_k<<<256, 64, 0, stream>>>(Amat + i * 4096, u, Slast);
        replay_k<<<256, 64, 0, stream>>>(Amat + i * 4096, Apow + i * 4096, u, Slast, Hs, flag + i);
        scan_seq_k<<<8, 64, 0, stream>>>(Amat + i * 4096, u, Hs, flag + i);
        if (i < 3)
            post3_k<false><<<512, 256, 0, stream>>>(Hs, w_c + i * 16384, bC + i * HD,
                                                    w_p + i * 65536, pb + i * HD, gB, xnb, hb,
                                                    lng + (i + 1) * HD, lnb + (i + 1) * HD);
        else
            post3_k<true><<<512, 256, 0, stream>>>(Hs, w_c + i * 16384, bC + i * HD,
                                                   w_p + i * 65536, pb + i * HD, gB, xnb, hb,
                                                   lng, lnb);
    }
    gemm_k<DOUT><<<dim3(128, 12), 256, 0, stream>>>(hb, w_o, ob, (float*)d_out);
}

// Round 19
// 407.643 us; speedup vs baseline: 1.0025x; 1.0025x over previous
//
#include <hip/hip_runtime.h>

typedef float f32x4 __attribute__((ext_vector_type(4)));
typedef short short8 __attribute__((ext_vector_type(8)));

#define T_LEN 2048
#define HD 256
#define SD 64
#define DIN 768
#define DOUT 768
#define NCHUNK 32
#define CLEN 64

#define SBAR() __builtin_amdgcn_sched_barrier(0)

__device__ __forceinline__ unsigned short f2bf(float f) {
    unsigned int u = __float_as_uint(f);
    unsigned int r = u + 0x7FFFu + ((u >> 16) & 1u);
    return (unsigned short)(r >> 16);
}
__device__ __forceinline__ float bf2f(unsigned short h) {
    return __uint_as_float(((unsigned int)h) << 16);
}
__device__ __forceinline__ int swz(int row, int col, int stride) {
    return row * stride + (col ^ ((row & 7) << 3));
}
#define GLL(gp, lp) __builtin_amdgcn_global_load_lds( \
    (const __attribute__((address_space(1))) void*)(gp), \
    (__attribute__((address_space(3))) void*)(lp), 16, 0, 0)

// ---------------- weight conversion ----------------
__global__ __launch_bounds__(256) void cvt_w_k(const float* __restrict__ s0, const float* __restrict__ s1,
                                               const float* __restrict__ s2, const float* __restrict__ s3,
                                               const float* __restrict__ s4, const float* __restrict__ s5,
                                               unsigned short* __restrict__ d) {
    int i = blockIdx.x * 256 + threadIdx.x;
    if (i >= 1048576) return;
    float v;
    if (i < 196608)      v = s0[i];
    else if (i < 262144) v = s1[i - 196608];
    else if (i < 524288) v = s2[i - 262144];
    else if (i < 786432) v = s3[i - 524288];
    else if (i < 851968) v = s4[i - 786432];
    else                 v = s5[i - 851968];
    d[i] = f2bf(v);
}

// ---------------- A^64 via bf16-split MFMA (6 squarings, verified) ----------------
__global__ __launch_bounds__(256) void matpow_k(const float* __restrict__ A, float* __restrict__ Apow) {
    __shared__ unsigned short Mh[4096], Ml[4096], MhT[4096], MlT[4096];
    const int l = blockIdx.x, tid = threadIdx.x;
    const int w = tid >> 6, ln = tid & 63, ll = ln & 15, lh = ln >> 4;
    const float* src = A + l * 4096;
    for (int i = tid; i < 4096; i += 256) {
        float v = src[i];
        unsigned short hi = f2bf(v);
        unsigned short lo = f2bf(v - bf2f(hi));
        int r = i >> 6, c = i & 63;
        Mh[swz(r, c, 64)] = hi;  Ml[swz(r, c, 64)] = lo;
        MhT[swz(c, r, 64)] = hi; MlT[swz(c, r, 64)] = lo;
    }
    __syncthreads();
    for (int it = 0; it < 6; it++) {
        f32x4 acc[4] = {};
#pragma unroll
        for (int ks = 0; ks < 2; ks++) {
            int ar = w * 16 + ll, c0 = ks * 32 + lh * 8;
            short8 ah = *reinterpret_cast<const short8*>(&Mh[swz(ar, c0, 64)]);
            short8 al = *reinterpret_cast<const short8*>(&Ml[swz(ar, c0, 64)]);
#pragma unroll
            for (int nf = 0; nf < 4; nf++) {
                int br = nf * 16 + ll;
                short8 bh = *reinterpret_cast<const short8*>(&MhT[swz(br, c0, 64)]);
                short8 bl = *reinterpret_cast<const short8*>(&MlT[swz(br, c0, 64)]);
                acc[nf] = __builtin_amdgcn_mfma_f32_16x16x32_bf16(ah, bh, acc[nf], 0, 0, 0);
                acc[nf] = __builtin_amdgcn_mfma_f32_16x16x32_bf16(ah, bl, acc[nf], 0, 0, 0);
                acc[nf] = __builtin_amdgcn_mfma_f32_16x16x32_bf16(al, bh, acc[nf], 0, 0, 0);
            }
        }
        __syncthreads();
#pragma unroll
        for (int nf = 0; nf < 4; nf++)
#pragma unroll
            for (int r = 0; r < 4; r++) {
                float v = acc[nf][r];
                int row = w * 16 + lh * 4 + r, col = nf * 16 + ll;
                unsigned short hi = f2bf(v);
                unsigned short lo = f2bf(v - bf2f(hi));
                Mh[swz(row, col, 64)] = hi;  Ml[swz(row, col, 64)] = lo;
                MhT[swz(col, row, 64)] = hi; MlT[swz(col, row, 64)] = lo;
            }
        __syncthreads();
    }
    for (int i = tid; i < 4096; i += 256) {
        int r = i >> 6, c = i & 63;
        Apow[l * 4096 + i] = bf2f(Mh[swz(r, c, 64)]) + bf2f(Ml[swz(r, c, 64)]);
    }
}

// ---------------- fused in-proj + LN, BM=32, BK=64, W staged via GLL (8-slot swizzle) ----------------
// Ws[256][64] bf16: content(row, s) = global(row, s ^ (row&7)), s = 16B-chunk 0..7
__global__ __launch_bounds__(256) void in_ln_k(const float* __restrict__ x,
                                               const unsigned short* __restrict__ w_in,
                                               const float* __restrict__ inb,
                                               const float* __restrict__ lng, const float* __restrict__ lnb,
                                               unsigned short* __restrict__ hb, unsigned short* __restrict__ xnb) {
    __shared__ unsigned short smem[16384 + 32 * 264];   // Ws 32KB + hnb 16.9KB
    unsigned short* Ws = smem;
    unsigned short* hnb = smem + 16384;
    const int tid = threadIdx.x, l = tid & 63, w = tid >> 6;
    const int ll = l & 15, lh = l >> 4;
    const int mf = w >> 1, nh = w & 1;
    const int m0 = blockIdx.x * 32;
    const int r8 = l >> 3;                       // 0..7
    const int csw = ((l & 7) ^ r8) * 8;          // pre-swizzled source chunk (elems)
    const float* ap = x + (size_t)(m0 + mf * 16 + ll) * DIN + lh * 8;
    const unsigned short* gwR = w_in + (size_t)(w * 8 + r8) * DIN + csw;
    unsigned short* lwR = Ws + (size_t)(w * 8) * 64 + l * 8;
    f32x4 acc[8] = {};
    for (int k0 = 0; k0 < DIN; k0 += 64) {
#pragma unroll
        for (int q = 0; q < 8; q++)
            GLL(gwR + (size_t)(q * 32) * DIN + k0, lwR + q * 32 * 64);
        short8 af[2];
#pragma unroll
        for (int ks = 0; ks < 2; ks++) {
            float4 a0 = *reinterpret_cast<const float4*>(ap + k0 + ks * 32);
            float4 a1 = *reinterpret_cast<const float4*>(ap + k0 + ks * 32 + 4);
            short8 t;
            t[0] = (short)f2bf(a0.x); t[1] = (short)f2bf(a0.y);
            t[2] = (short)f2bf(a0.z); t[3] = (short)f2bf(a0.w);
            t[4] = (short)f2bf(a1.x); t[5] = (short)f2bf(a1.y);
            t[6] = (short)f2bf(a1.z); t[7] = (short)f2bf(a1.w);
            af[ks] = t;
        }
        __syncthreads();
#pragma unroll
        for (int ks = 0; ks < 2; ks++) {
            const int so = (((ks * 4 + lh) ^ (ll & 7)) * 8);
#pragma unroll
            for (int j = 0; j < 8; j++) {
                short8 b = *reinterpret_cast<const short8*>(&Ws[(size_t)(nh * 128 + j * 16 + ll) * 64 + so]);
                acc[j] = __builtin_amdgcn_mfma_f32_16x16x32_bf16(af[ks], b, acc[j], 0, 0, 0);
            }
        }
        __syncthreads();
    }
#pragma unroll
    for (int j = 0; j < 8; j++)
#pragma unroll
        for (int r = 0; r < 4; r++) {
            int rowl = mf * 16 + lh * 4 + r;
            int col = nh * 128 + j * 16 + ll;
            hnb[rowl * 264 + col] = f2bf(acc[j][r] + inb[col]);
        }
    __syncthreads();
#pragma unroll
    for (int q = 0; q < 8; q++) {
        int rowl = w * 8 + q;
        size_t gidx = (size_t)(m0 + rowl) * HD + l * 4;
        ushort4 hv = *reinterpret_cast<const ushort4*>(&hnb[rowl * 264 + l * 4]);
        float o0 = bf2f(hv.x), o1 = bf2f(hv.y), o2 = bf2f(hv.z), o3 = bf2f(hv.w);
        float s = o0 + o1 + o2 + o3;
        float s2 = o0 * o0 + o1 * o1 + o2 * o2 + o3 * o3;
#pragma unroll
        for (int mm = 1; mm < 64; mm <<= 1) { s += __shfl_xor(s, mm); s2 += __shfl_xor(s2, mm); }
        float mean = s * (1.f / 256.f);
        float var = s2 * (1.f / 256.f) - mean * mean;
        float rstd = rsqrtf(var + 1e-5f);
        int c = l * 4;
        *reinterpret_cast<ushort4*>(hb + gidx) = hv;
        ushort4 xo;
        xo.x = f2bf((o0 - mean) * rstd * lng[c + 0] + lnb[c + 0]);
        xo.y = f2bf((o1 - mean) * rstd * lng[c + 1] + lnb[c + 1]);
        xo.z = f2bf((o2 - mean) * rstd * lng[c + 2] + lnb[c + 2]);
        xo.w = f2bf((o3 - mean) * rstd * lng[c + 3] + lnb[c + 3]);
        *reinterpret_cast<ushort4*>(xnb + gidx) = xo;
    }
}

// ---------------- staged GEMM core, K=256, BK=64 (8-slot swizzle) ----------------
// As[128][64] 16KB + Bs[64][64] 8KB. 4 k-steps x {6 GLL + 16 MFMA}.
__device__ __forceinline__ void staged_core256(const unsigned short* __restrict__ A, int m0b,
                                               const unsigned short* __restrict__ W, int n0,
                                               unsigned short* As, unsigned short* Bs,
                                               int tid, f32x4 (*acc)[4]) {
    const int l = tid & 63, w = tid >> 6;
    const int ll = l & 15, lh = l >> 4;
    const int r8 = l >> 3;
    const int csw = ((l & 7) ^ r8) * 8;
    const unsigned short* gaR = A + (size_t)(m0b + w * 8 + r8) * 256 + csw;
    const unsigned short* gbR = W + (size_t)(n0 + w * 8 + r8) * 256 + csw;
    unsigned short* laR = As + (size_t)(w * 8) * 64 + l * 8;
    unsigned short* lbR = Bs + (size_t)(w * 8) * 64 + l * 8;
#pragma unroll
    for (int k0 = 0; k0 < 256; k0 += 64) {
#pragma unroll
        for (int q = 0; q < 4; q++)
            GLL(gaR + (size_t)(q * 32) * 256 + k0, laR + q * 32 * 64);
#pragma unroll
        for (int q = 0; q < 2; q++)
            GLL(gbR + (size_t)(q * 32) * 256 + k0, lbR + q * 32 * 64);
        __syncthreads();
#pragma unroll
        for (int ks = 0; ks < 2; ks++) {
            const int so = (((ks * 4 + lh) ^ (ll & 7)) * 8);
            short8 a0 = *reinterpret_cast<const short8*>(&As[(size_t)(w * 32 + ll) * 64 + so]);
            short8 a1 = *reinterpret_cast<const short8*>(&As[(size_t)(w * 32 + 16 + ll) * 64 + so]);
            short8 b0 = *reinterpret_cast<const short8*>(&Bs[(size_t)(ll) * 64 + so]);
            short8 b1 = *reinterpret_cast<const short8*>(&Bs[(size_t)(16 + ll) * 64 + so]);
            short8 b2 = *reinterpret_cast<const short8*>(&Bs[(size_t)(32 + ll) * 64 + so]);
            short8 b3 = *reinterpret_cast<const short8*>(&Bs[(size_t)(48 + ll) * 64 + so]);
            acc[0][0] = __builtin_amdgcn_mfma_f32_16x16x32_bf16(a0, b0, acc[0][0], 0, 0, 0);
            acc[0][1] = __builtin_amdgcn_mfma_f32_16x16x32_bf16(a0, b1, acc[0][1], 0, 0, 0);
            acc[0][2] = __builtin_amdgcn_mfma_f32_16x16x32_bf16(a0, b2, acc[0][2], 0, 0, 0);
            acc[0][3] = __builtin_amdgcn_mfma_f32_16x16x32_bf16(a0, b3, acc[0][3], 0, 0, 0);
            acc[1][0] = __builtin_amdgcn_mfma_f32_16x16x32_bf16(a1, b0, acc[1][0], 0, 0, 0);
            acc[1][1] = __builtin_amdgcn_mfma_f32_16x16x32_bf16(a1, b1, acc[1][1], 0, 0, 0);
            acc[1][2] = __builtin_amdgcn_mfma_f32_16x16x32_bf16(a1, b2, acc[1][2], 0, 0, 0);
            acc[1][3] = __builtin_amdgcn_mfma_f32_16x16x32_bf16(a1, b3, acc[1][3], 0, 0, 0);
        }
        __syncthreads();
    }
}

// ---------------- final GEMM, staged, fp32 out, nontemporal stores ----------------
template <int N>
__global__ __launch_bounds__(256) void gemm_k(const unsigned short* __restrict__ A,
                                              const unsigned short* __restrict__ W,
                                              const float* __restrict__ bias,
                                              float* __restrict__ outf) {
    __shared__ char smem[128 * 68 * 4];   // staging 24KB aliased under epilogue 34.8KB
    unsigned short* As = (unsigned short*)smem;
    unsigned short* Bs = As + 8192;
    float* sf = (float*)smem;
    const int tid = threadIdx.x, l = tid & 63, w = tid >> 6;
    const int ll = l & 15, lh = l >> 4;
    const int m0b = blockIdx.x * 128;
    const int n0 = blockIdx.y * 64;
    f32x4 acc[2][4] = {};
    staged_core256(A, m0b, W, n0, As, Bs, tid, acc);
#pragma unroll
    for (int mf = 0; mf < 2; mf++)
#pragma unroll
        for (int nf = 0; nf < 4; nf++)
#pragma unroll
            for (int r = 0; r < 4; r++) {
                int rowl = w * 32 + mf * 16 + lh * 4 + r;
                int col = nf * 16 + ll;
                sf[rowl * 68 + col] = acc[mf][nf][r] + bias[n0 + col];
            }
    __syncthreads();
#pragma unroll
    for (int p = 0; p < 8; p++) {
        int rowl = p * 16 + (tid >> 4);
        int col = (tid & 15) * 4;
        f32x4 v = *reinterpret_cast<const f32x4*>(&sf[rowl * 68 + col]);
        __builtin_nontemporal_store(v, reinterpret_cast<f32x4*>(outf + (size_t)(m0b + rowl) * N + n0 + col));
    }
}

// ---------------- fused gate + ip GEMM, staged, BM=128 (grid y: 0..3 gate, 4 = ip) ----------------
__global__ __launch_bounds__(256) void gateip_k(const unsigned short* __restrict__ xnb,
                                                const unsigned short* __restrict__ wg,
                                                const unsigned short* __restrict__ wip,
                                                const float* __restrict__ gbias, const float* __restrict__ ipb,
                                                const float* __restrict__ Bv, const float* __restrict__ bA,
                                                unsigned short* __restrict__ gB, float* __restrict__ u) {
    __shared__ char smem[128 * 68 * 4];
    unsigned short* As = (unsigned short*)smem;
    unsigned short* Bs = As + 8192;
    float* sf = (float*)smem;
    unsigned short* su = (unsigned short*)smem;
    const int tid = threadIdx.x, l = tid & 63, w = tid >> 6;
    const int ll = l & 15, lh = l >> 4;
    const int m0b = blockIdx.x * 128;
    const int y = blockIdx.y;
    const bool gate = (y < 4);
    const int n0 = gate ? y * 64 : 0;
    f32x4 acc[2][4] = {};
    staged_core256(xnb, m0b, gate ? wg : wip, n0, As, Bs, tid, acc);
    if (gate) {
#pragma unroll
        for (int mf = 0; mf < 2; mf++)
#pragma unroll
            for (int nf = 0; nf < 4; nf++)
#pragma unroll
                for (int r = 0; r < 4; r++) {
                    int rowl = w * 32 + mf * 16 + lh * 4 + r;
                    int col = nf * 16 + ll;
                    float v = acc[mf][nf][r] + gbias[n0 + col];
                    su[rowl * 72 + col] = f2bf(1.f / (1.f + __expf(-v)));
                }
        __syncthreads();
#pragma unroll
        for (int p = 0; p < 8; p++) {
            int rowl = p * 16 + (tid >> 4);
            int col = (tid & 15) * 4;
            ushort4 v = *reinterpret_cast<const ushort4*>(&su[rowl * 72 + col]);
            *reinterpret_cast<ushort4*>(gB + (size_t)(m0b + rowl) * HD + n0 + col) = v;
        }
    } else {
#pragma unroll
        for (int mf = 0; mf < 2; mf++)
#pragma unroll
            for (int nf = 0; nf < 4; nf++)
#pragma unroll
                for (int r = 0; r < 4; r++) {
                    int rowl = w * 32 + mf * 16 + lh * 4 + r;
                    int col = nf * 16 + ll;
                    float v = acc[mf][nf][r] + ipb[col];
                    sf[rowl * 68 + col] = Bv[col] * v + bA[col];
                }
        __syncthreads();
#pragma unroll
        for (int p = 0; p < 8; p++) {
            int rowl = p * 16 + (tid >> 4);
            int col = (tid & 15) * 4;
            int m = m0b + rowl;           // bt-order
            int t = m & 2047, b2 = m >> 11;
            float4 v = *reinterpret_cast<const float4*>(&sf[rowl * 68 + col]);
            *reinterpret_cast<float4*>(u + ((size_t)((t << 3) + b2)) * 64 + col) = v;
        }
    }
}

// ---------------- fused Cm + proj + blend + LN(next layer); bf16 residual ----------------
template <bool LAST>
__global__ __launch_bounds__(256) void post3_k(const unsigned short* __restrict__ Hs,
                                               const unsigned short* __restrict__ wc,
                                               const float* __restrict__ bC,
                                               const unsigned short* __restrict__ wp,
                                               const float* __restrict__ pb,
                                               const unsigned short* __restrict__ gB,
                                               unsigned short* __restrict__ xnb,
                                               unsigned short* __restrict__ hb,
                                               const float* __restrict__ lng2, const float* __restrict__ lnb2) {
    __shared__ unsigned short ys[32 * 256];
    __shared__ unsigned short hnb[32 * 264];
    const int tid = threadIdx.x, l = tid & 63, w = tid >> 6;
    const int ll = l & 15, lh = l >> 4;
    const int mf = w >> 1, nh = w & 1;
    const int m0 = blockIdx.x * 32;          // tb-order
    {
        short8 ha[2], cb[8][2];
        const unsigned short* Ap = Hs + (size_t)(m0 + mf * 16 + ll) * SD + lh * 8;
#pragma unroll
        for (int ks = 0; ks < 2; ks++)
            ha[ks] = *reinterpret_cast<const short8*>(Ap + ks * 32);
#pragma unroll
        for (int ks = 0; ks < 2; ks++)
#pragma unroll
            for (int j = 0; j < 8; j++)
                cb[j][ks] = *reinterpret_cast<const short8*>(wc + (size_t)((nh * 8 + j) * 16 + ll) * SD + ks * 32 + lh * 8);
        SBAR();
        f32x4 acc[8] = {};
#pragma unroll
        for (int ks = 0; ks < 2; ks++)
#pragma unroll
            for (int j = 0; j < 8; j++)
                acc[j] = __builtin_amdgcn_mfma_f32_16x16x32_bf16(ha[ks], cb[j][ks], acc[j], 0, 0, 0);
#pragma unroll
        for (int j = 0; j < 8; j++)
#pragma unroll
            for (int r = 0; r < 4; r++) {
                int rowl = mf * 16 + lh * 4 + r;
                int col = (nh * 8 + j) * 16 + ll;
                ys[swz(rowl, col, 256)] = f2bf(acc[j][r] + bC[col]);
            }
    }
    __syncthreads();
    {
        f32x4 acc2[8] = {};
        const int arow = mf * 16 + ll;
#pragma unroll
        for (int kb = 0; kb < 4; kb++) {
            short8 pwf[8][2];
#pragma unroll
            for (int ks = 0; ks < 2; ks++)
#pragma unroll
                for (int j = 0; j < 8; j++)
                    pwf[j][ks] = *reinterpret_cast<const short8*>(wp + (size_t)((nh * 8 + j) * 16 + ll) * HD + kb * 64 + ks * 32 + lh * 8);
            SBAR();
#pragma unroll
            for (int ks = 0; ks < 2; ks++) {
                int c0 = kb * 64 + ks * 32 + lh * 8;
                short8 a = *reinterpret_cast<const short8*>(&ys[swz(arow, c0, 256)]);
#pragma unroll
                for (int j = 0; j < 8; j++)
                    acc2[j] = __builtin_amdgcn_mfma_f32_16x16x32_bf16(a, pwf[j][ks], acc2[j], 0, 0, 0);
            }
        }
#pragma unroll
        for (int j = 0; j < 8; j++)
#pragma unroll
            for (int r = 0; r < 4; r++) {
                int rowl = mf * 16 + lh * 4 + r;
                int col = (nh * 8 + j) * 16 + ll;
                hnb[rowl * 264 + col] = f2bf(acc2[j][r] + pb[col]);
            }
    }
    __syncthreads();
#pragma unroll
    for (int q = 0; q < 8; q++) {
        int rowl = w * 8 + q;
        int m = m0 + rowl;               // tb-order
        int t = m >> 3, b2 = m & 7;
        size_t gidx = ((size_t)((b2 << 11) + t)) * HD + l * 4;
        ushort4 hv = *reinterpret_cast<const ushort4*>(hb + gidx);
        ushort4 gv = *reinterpret_cast<const ushort4*>(gB + gidx);
        ushort4 xv = *reinterpret_cast<const ushort4*>(xnb + gidx);
        ushort4 yv = *reinterpret_cast<const ushort4*>(&hnb[rowl * 264 + l * 4]);
        float g0 = bf2f(gv.x), g1 = bf2f(gv.y), g2 = bf2f(gv.z), g3 = bf2f(gv.w);
        float o0 = bf2f(hv.x) + g0 * bf2f(yv.x) + (1.f - g0) * bf2f(xv.x);
        float o1 = bf2f(hv.y) + g1 * bf2f(yv.y) + (1.f - g1) * bf2f(xv.y);
        float o2 = bf2f(hv.z) + g2 * bf2f(yv.z) + (1.f - g2) * bf2f(xv.z);
        float o3 = bf2f(hv.w) + g3 * bf2f(yv.w) + (1.f - g3) * bf2f(xv.w);
        ushort4 hbv;
        hbv.x = f2bf(o0); hbv.y = f2bf(o1); hbv.z = f2bf(o2); hbv.w = f2bf(o3);
        *reinterpret_cast<ushort4*>(hb + gidx) = hbv;
        if constexpr (!LAST) {
            float s = o0 + o1 + o2 + o3;
            float s2 = o0 * o0 + o1 * o1 + o2 * o2 + o3 * o3;
#pragma unroll
            for (int mm = 1; mm < 64; mm <<= 1) { s += __shfl_xor(s, mm); s2 += __shfl_xor(s2, mm); }
            float mean = s * (1.f / 256.f);
            float var = s2 * (1.f / 256.f) - mean * mean;
            float rstd = rsqrtf(var + 1e-5f);
            int c = l * 4;
            ushort4 xo;
            xo.x = f2bf((o0 - mean) * rstd * lng2[c + 0] + lnb2[c + 0]);
            xo.y = f2bf((o1 - mean) * rstd * lng2[c + 1] + lnb2[c + 1]);
            xo.z = f2bf((o2 - mean) * rstd * lng2[c + 2] + lnb2[c + 2]);
            xo.w = f2bf((o3 - mean) * rstd * lng2[c + 3] + lnb2[c + 3]);
            *reinterpret_cast<ushort4*>(xnb + gidx) = xo;
        }
    }
}

// ---------------- scan helpers ----------------
__device__ __forceinline__ void loadA64(const float* __restrict__ Af, int s, float* a) {
#pragma unroll
    for (int q = 0; q < 16; q++) {
        float4 v = reinterpret_cast<const float4*>(Af + s * 64)[q];
        a[q * 4 + 0] = v.x; a[q * 4 + 1] = v.y; a[q * 4 + 2] = v.z; a[q * 4 + 3] = v.w;
    }
}

__device__ __forceinline__ float step64(const float* a, float h, float uu) {
    float ac0 = uu, ac1 = 0.f, ac2 = 0.f, ac3 = 0.f;
#pragma unroll
    for (int k = 0; k < 64; k += 4) {
        float b0 = __int_as_float(__builtin_amdgcn_readlane(__float_as_int(h), k + 0));
        float b1 = __int_as_float(__builtin_amdgcn_readlane(__float_as_int(h), k + 1));
        float b2 = __int_as_float(__builtin_amdgcn_readlane(__float_as_int(h), k + 2));
        float b3 = __int_as_float(__builtin_amdgcn_readlane(__float_as_int(h), k + 3));
        ac0 = fmaf(b0, a[k + 0], ac0);
        ac1 = fmaf(b1, a[k + 1], ac1);
        ac2 = fmaf(b2, a[k + 2], ac2);
        ac3 = fmaf(b3, a[k + 3], ac3);
    }
    return (ac0 + ac1) + (ac2 + ac3);
}

__global__ __launch_bounds__(64) void scan_chunk_k(const float* __restrict__ Af,
                                                   const float* __restrict__ u,
                                                   float* __restrict__ Slast) {
    const int c = blockIdx.x >> 3, b = blockIdx.x & 7;
    const int s = threadIdx.x;
    float a[64];
    loadA64(Af, s, a);
    const float* up = u + (c * CLEN) * 512 + b * 64 + s;
    float uv[CLEN];
#pragma unroll
    for (int i = 0; i < CLEN; i++) uv[i] = up[i * 512];
    float h = 0.f;
#pragma unroll
    for (int i = 0; i < CLEN; i++) h = step64(a, h, uv[i]);
    Slast[blockIdx.x * 64 + s] = h;
}

__global__ __launch_bounds__(64) void replay_k(const float* __restrict__ Af,
                                               const float* __restrict__ Apow,
                                               const float* __restrict__ u,
                                               const float* __restrict__ Slast,
                                               unsigned short* __restrict__ Hs,
                                               int* __restrict__ flag) {
    const int c = blockIdx.x >> 3, b = blockIdx.x & 7;
    const int s = threadIdx.x;
    float a[64];
    float carry = 0.f;
    if (c > 0) {
        loadA64(Apow, s, a);
        for (int j = 0; j < c; j++) {
            float sl = Slast[(j * 8 + b) * 64 + s];
            carry = step64(a, carry, sl);
        }
    }
    loadA64(Af, s, a);
    const float* up = u + (c * CLEN) * 512 + b * 64 + s;
    float uv[CLEN];
#pragma unroll
    for (int i = 0; i < CLEN; i++) uv[i] = up[i * 512];
    float h = carry;
    unsigned short* hp = Hs + (c * CLEN) * 512 + b * 64 + s;
    bool bad = false;
#pragma unroll
    for (int i = 0; i < CLEN; i++) {
        h = step64(a, h, uv[i]);
        bad |= (fabsf(h) > 10.f);
        hp[i * 512] = f2bf(h);
    }
    if (__any(bad ? 1 : 0)) {
        if (s == 0) atomicOr(flag, 1);
    }
}

__global__ __launch_bounds__(64) void scan_seq_k(const float* __restrict__ Af,
                                                 const float* __restrict__ u,
                                                 unsigned short* __restrict__ Hs,
                                                 const int* __restrict__ flag) {
    if (*flag == 0) return;
    const int b = blockIdx.x;
    const int s = threadIdx.x;
    float a[64];
    loadA64(Af, s, a);
    float h = 0.f;
    for (int t = 0; t < T_LEN; t++) {
        float uu = u[((t << 3) + b) * 64 + s];
        float hp = step64(a, h, uu);
        h = fminf(fmaxf(hp, -10.f), 10.f);
        Hs[((t << 3) + b) * 64 + s] = f2bf(h);
    }
}

// ---------------- launch ----------------
extern "C" void kernel_launch(void* const* d_in, const int* in_sizes, int n_in,
                              void* d_out, int out_size, void* d_ws, size_t ws_size,
                              hipStream_t stream) {
    const float* x    = (const float*)d_in[0];
    const float* inw  = (const float*)d_in[1];
    const float* inb  = (const float*)d_in[2];
    const float* lng  = (const float*)d_in[3];
    const float* lnb  = (const float*)d_in[4];
    const float* ipw  = (const float*)d_in[5];
    const float* ipb  = (const float*)d_in[6];
    const float* Amat = (const float*)d_in[7];
    const float* Bv   = (const float*)d_in[8];
    const float* Cm   = (const float*)d_in[9];
    const float* bA   = (const float*)d_in[10];
    const float* bC   = (const float*)d_in[11];
    const float* gw   = (const float*)d_in[12];
    const float* gbia = (const float*)d_in[13];
    const float* pw   = (const float*)d_in[14];
    const float* pb   = (const float*)d_in[15];
    const float* ow   = (const float*)d_in[16];
    const float* ob   = (const float*)d_in[17];

    char* ws = (char*)d_ws;
    float*          u  = (float*)(ws + 0);                   // 4 MB
    unsigned short* Hs = (unsigned short*)(ws + 4194304);    // 2 MB
    unsigned short* hb = (unsigned short*)(ws + 14680064);   // 8 MB (bf16 residual)
    unsigned short* wb = (unsigned short*)(ws + 25165824);   // 2 MB
    unsigned short* xnb = (unsigned short*)(ws + 44040192);  // 8 MB
    unsigned short* gB  = (unsigned short*)(ws + 52428800);  // 8 MB

    char* sc = (char*)d_out;   // small scratch; fully overwritten by final GEMM
    float* Apow  = (float*)(sc + 0);          // 64 KB: [4][64][64] (A^64)
    float* Slast = (float*)(sc + 65536);      // 64 KB
    int*   flag  = (int*)(sc + 196608);       // 16 B

    const unsigned short* w_in = wb + 0;
    const unsigned short* w_ip = wb + 196608;
    const unsigned short* w_g  = wb + 262144;
    const unsigned short* w_p  = wb + 524288;
    const unsigned short* w_c  = wb + 786432;
    const unsigned short* w_o  = wb + 851968;

    hipMemsetAsync(flag, 0, 16, stream);
    cvt_w_k<<<4096, 256, 0, stream>>>(inw, ipw, gw, pw, Cm, ow, wb);
    matpow_k<<<4, 256, 0, stream>>>(Amat, Apow);

    in_ln_k<<<512, 256, 0, stream>>>(x, w_in, inb, lng, lnb, hb, xnb);
    for (int i = 0; i < 4; i++) {
        gateip_k<<<dim3(128, 5), 256, 0, stream>>>(xnb, w_g + i * 65536, w_ip + i * 16384,
                                                   gbia + i * HD, ipb + i * SD,
                                                   Bv + i * SD, bA + i * SD, gB, u);
        scan_chunk_k<<<256, 64, 0, stream>>>(Amat + i * 4096, u, Slast);
        replay_k<<<256, 64, 0, stream>>>(Amat + i * 4096, Apow + i * 4096, u, Slast, Hs, flag + i);
        scan_seq_k<<<8, 64, 0, stream>>>(Amat + i * 4096, u, Hs, flag + i);
        if (i < 3)
            post3_k<false><<<512, 256, 0, stream>>>(Hs, w_c + i * 16384, bC + i * HD,
                                                    w_p + i * 65536, pb + i * HD, gB, xnb, hb,
                                                    lng + (i + 1) * HD, lnb + (i + 1) * HD);
        else
            post3_k<true><<<512, 256, 0, stream>>>(Hs, w_c + i * 16384, bC + i * HD,
                                                   w_p + i * 65536, pb + i * HD, gB, xnb, hb,
                                                   lng, lnb);
    }
    gemm_k<DOUT><<<dim3(128, 12), 256, 0, stream>>>(hb, w_o, ob, (float*)d_out);
}

// Round 20
// 367.666 us; speedup vs baseline: 1.1116x; 1.1087x over previous
//
#include <hip/hip_runtime.h>

typedef float f32x4 __attribute__((ext_vector_type(4)));
typedef short short8 __attribute__((ext_vector_type(8)));

#define T_LEN 2048
#define HD 256
#define SD 64
#define DIN 768
#define DOUT 768
#define NCHUNK 32
#define CLEN 64

#define SBAR() __builtin_amdgcn_sched_barrier(0)

__device__ __forceinline__ unsigned short f2bf(float f) {
    unsigned int u = __float_as_uint(f);
    unsigned int r = u + 0x7FFFu + ((u >> 16) & 1u);
    return (unsigned short)(r >> 16);
}
__device__ __forceinline__ float bf2f(unsigned short h) {
    return __uint_as_float(((unsigned int)h) << 16);
}
__device__ __forceinline__ int swz(int row, int col, int stride) {
    return row * stride + (col ^ ((row & 7) << 3));
}
#define GLL(gp, lp) __builtin_amdgcn_global_load_lds( \
    (const __attribute__((address_space(1))) void*)(gp), \
    (__attribute__((address_space(3))) void*)(lp), 16, 0, 0)

// ---------------- weight conversion ----------------
__global__ __launch_bounds__(256) void cvt_w_k(const float* __restrict__ s0, const float* __restrict__ s1,
                                               const float* __restrict__ s2, const float* __restrict__ s3,
                                               const float* __restrict__ s4, const float* __restrict__ s5,
                                               unsigned short* __restrict__ d) {
    int i = blockIdx.x * 256 + threadIdx.x;
    if (i >= 1048576) return;
    float v;
    if (i < 196608)      v = s0[i];
    else if (i < 262144) v = s1[i - 196608];
    else if (i < 524288) v = s2[i - 262144];
    else if (i < 786432) v = s3[i - 524288];
    else if (i < 851968) v = s4[i - 786432];
    else                 v = s5[i - 851968];
    d[i] = f2bf(v);
}

// ---------------- A^64 via bf16-split MFMA (6 squarings, verified) ----------------
__global__ __launch_bounds__(256) void matpow_k(const float* __restrict__ A, float* __restrict__ Apow) {
    __shared__ unsigned short Mh[4096], Ml[4096], MhT[4096], MlT[4096];
    const int l = blockIdx.x, tid = threadIdx.x;
    const int w = tid >> 6, ln = tid & 63, ll = ln & 15, lh = ln >> 4;
    const float* src = A + l * 4096;
    for (int i = tid; i < 4096; i += 256) {
        float v = src[i];
        unsigned short hi = f2bf(v);
        unsigned short lo = f2bf(v - bf2f(hi));
        int r = i >> 6, c = i & 63;
        Mh[swz(r, c, 64)] = hi;  Ml[swz(r, c, 64)] = lo;
        MhT[swz(c, r, 64)] = hi; MlT[swz(c, r, 64)] = lo;
    }
    __syncthreads();
    for (int it = 0; it < 6; it++) {
        f32x4 acc[4] = {};
#pragma unroll
        for (int ks = 0; ks < 2; ks++) {
            int ar = w * 16 + ll, c0 = ks * 32 + lh * 8;
            short8 ah = *reinterpret_cast<const short8*>(&Mh[swz(ar, c0, 64)]);
            short8 al = *reinterpret_cast<const short8*>(&Ml[swz(ar, c0, 64)]);
#pragma unroll
            for (int nf = 0; nf < 4; nf++) {
                int br = nf * 16 + ll;
                short8 bh = *reinterpret_cast<const short8*>(&MhT[swz(br, c0, 64)]);
                short8 bl = *reinterpret_cast<const short8*>(&MlT[swz(br, c0, 64)]);
                acc[nf] = __builtin_amdgcn_mfma_f32_16x16x32_bf16(ah, bh, acc[nf], 0, 0, 0);
                acc[nf] = __builtin_amdgcn_mfma_f32_16x16x32_bf16(ah, bl, acc[nf], 0, 0, 0);
                acc[nf] = __builtin_amdgcn_mfma_f32_16x16x32_bf16(al, bh, acc[nf], 0, 0, 0);
            }
        }
        __syncthreads();
#pragma unroll
        for (int nf = 0; nf < 4; nf++)
#pragma unroll
            for (int r = 0; r < 4; r++) {
                float v = acc[nf][r];
                int row = w * 16 + lh * 4 + r, col = nf * 16 + ll;
                unsigned short hi = f2bf(v);
                unsigned short lo = f2bf(v - bf2f(hi));
                Mh[swz(row, col, 64)] = hi;  Ml[swz(row, col, 64)] = lo;
                MhT[swz(col, row, 64)] = hi; MlT[swz(col, row, 64)] = lo;
            }
        __syncthreads();
    }
    for (int i = tid; i < 4096; i += 256) {
        int r = i >> 6, c = i & 63;
        Apow[l * 4096 + i] = bf2f(Mh[swz(r, c, 64)]) + bf2f(Ml[swz(r, c, 64)]);
    }
}

// ---------------- fused in-proj + LN, BM=32, BK=64, W staged (8-slot swizzle) ----------------
__global__ __launch_bounds__(256) void in_ln_k(const float* __restrict__ x,
                                               const unsigned short* __restrict__ w_in,
                                               const float* __restrict__ inb,
                                               const float* __restrict__ lng, const float* __restrict__ lnb,
                                               unsigned short* __restrict__ hb, unsigned short* __restrict__ xnb) {
    __shared__ unsigned short smem[16384 + 32 * 264];   // Ws 32KB + hnb 16.9KB
    unsigned short* Ws = smem;
    unsigned short* hnb = smem + 16384;
    const int tid = threadIdx.x, l = tid & 63, w = tid >> 6;
    const int ll = l & 15, lh = l >> 4;
    const int mf = w >> 1, nh = w & 1;
    const int m0 = blockIdx.x * 32;
    const int r8 = l >> 3;
    const int csw = ((l & 7) ^ r8) * 8;
    const float* ap = x + (size_t)(m0 + mf * 16 + ll) * DIN + lh * 8;
    const unsigned short* gwR = w_in + (size_t)(w * 8 + r8) * DIN + csw;
    unsigned short* lwR = Ws + (size_t)(w * 8) * 64 + l * 8;
    f32x4 acc[8] = {};
    for (int k0 = 0; k0 < DIN; k0 += 64) {
#pragma unroll
        for (int q = 0; q < 8; q++)
            GLL(gwR + (size_t)(q * 32) * DIN + k0, lwR + q * 32 * 64);
        short8 af[2];
#pragma unroll
        for (int ks = 0; ks < 2; ks++) {
            float4 a0 = *reinterpret_cast<const float4*>(ap + k0 + ks * 32);
            float4 a1 = *reinterpret_cast<const float4*>(ap + k0 + ks * 32 + 4);
            short8 t;
            t[0] = (short)f2bf(a0.x); t[1] = (short)f2bf(a0.y);
            t[2] = (short)f2bf(a0.z); t[3] = (short)f2bf(a0.w);
            t[4] = (short)f2bf(a1.x); t[5] = (short)f2bf(a1.y);
            t[6] = (short)f2bf(a1.z); t[7] = (short)f2bf(a1.w);
            af[ks] = t;
        }
        __syncthreads();
#pragma unroll
        for (int ks = 0; ks < 2; ks++) {
            const int so = (((ks * 4 + lh) ^ (ll & 7)) * 8);
#pragma unroll
            for (int j = 0; j < 8; j++) {
                short8 b = *reinterpret_cast<const short8*>(&Ws[(size_t)(nh * 128 + j * 16 + ll) * 64 + so]);
                acc[j] = __builtin_amdgcn_mfma_f32_16x16x32_bf16(af[ks], b, acc[j], 0, 0, 0);
            }
        }
        __syncthreads();
    }
#pragma unroll
    for (int j = 0; j < 8; j++)
#pragma unroll
        for (int r = 0; r < 4; r++) {
            int rowl = mf * 16 + lh * 4 + r;
            int col = nh * 128 + j * 16 + ll;
            hnb[rowl * 264 + col] = f2bf(acc[j][r] + inb[col]);
        }
    __syncthreads();
#pragma unroll
    for (int q = 0; q < 8; q++) {
        int rowl = w * 8 + q;
        size_t gidx = (size_t)(m0 + rowl) * HD + l * 4;
        ushort4 hv = *reinterpret_cast<const ushort4*>(&hnb[rowl * 264 + l * 4]);
        float o0 = bf2f(hv.x), o1 = bf2f(hv.y), o2 = bf2f(hv.z), o3 = bf2f(hv.w);
        float s = o0 + o1 + o2 + o3;
        float s2 = o0 * o0 + o1 * o1 + o2 * o2 + o3 * o3;
#pragma unroll
        for (int mm = 1; mm < 64; mm <<= 1) { s += __shfl_xor(s, mm); s2 += __shfl_xor(s2, mm); }
        float mean = s * (1.f / 256.f);
        float var = s2 * (1.f / 256.f) - mean * mean;
        float rstd = rsqrtf(var + 1e-5f);
        int c = l * 4;
        *reinterpret_cast<ushort4*>(hb + gidx) = hv;
        ushort4 xo;
        xo.x = f2bf((o0 - mean) * rstd * lng[c + 0] + lnb[c + 0]);
        xo.y = f2bf((o1 - mean) * rstd * lng[c + 1] + lnb[c + 1]);
        xo.z = f2bf((o2 - mean) * rstd * lng[c + 2] + lnb[c + 2]);
        xo.w = f2bf((o3 - mean) * rstd * lng[c + 3] + lnb[c + 3]);
        *reinterpret_cast<ushort4*>(xnb + gidx) = xo;
    }
}

// ---------------- staged GEMM core, K=256, BK=64 (8-slot swizzle) ----------------
__device__ __forceinline__ void staged_core256(const unsigned short* __restrict__ A, int m0b,
                                               const unsigned short* __restrict__ W, int n0,
                                               unsigned short* As, unsigned short* Bs,
                                               int tid, f32x4 (*acc)[4]) {
    const int l = tid & 63, w = tid >> 6;
    const int ll = l & 15, lh = l >> 4;
    const int r8 = l >> 3;
    const int csw = ((l & 7) ^ r8) * 8;
    const unsigned short* gaR = A + (size_t)(m0b + w * 8 + r8) * 256 + csw;
    const unsigned short* gbR = W + (size_t)(n0 + w * 8 + r8) * 256 + csw;
    unsigned short* laR = As + (size_t)(w * 8) * 64 + l * 8;
    unsigned short* lbR = Bs + (size_t)(w * 8) * 64 + l * 8;
#pragma unroll
    for (int k0 = 0; k0 < 256; k0 += 64) {
#pragma unroll
        for (int q = 0; q < 4; q++)
            GLL(gaR + (size_t)(q * 32) * 256 + k0, laR + q * 32 * 64);
#pragma unroll
        for (int q = 0; q < 2; q++)
            GLL(gbR + (size_t)(q * 32) * 256 + k0, lbR + q * 32 * 64);
        __syncthreads();
#pragma unroll
        for (int ks = 0; ks < 2; ks++) {
            const int so = (((ks * 4 + lh) ^ (ll & 7)) * 8);
            short8 a0 = *reinterpret_cast<const short8*>(&As[(size_t)(w * 32 + ll) * 64 + so]);
            short8 a1 = *reinterpret_cast<const short8*>(&As[(size_t)(w * 32 + 16 + ll) * 64 + so]);
            short8 b0 = *reinterpret_cast<const short8*>(&Bs[(size_t)(ll) * 64 + so]);
            short8 b1 = *reinterpret_cast<const short8*>(&Bs[(size_t)(16 + ll) * 64 + so]);
            short8 b2 = *reinterpret_cast<const short8*>(&Bs[(size_t)(32 + ll) * 64 + so]);
            short8 b3 = *reinterpret_cast<const short8*>(&Bs[(size_t)(48 + ll) * 64 + so]);
            acc[0][0] = __builtin_amdgcn_mfma_f32_16x16x32_bf16(a0, b0, acc[0][0], 0, 0, 0);
            acc[0][1] = __builtin_amdgcn_mfma_f32_16x16x32_bf16(a0, b1, acc[0][1], 0, 0, 0);
            acc[0][2] = __builtin_amdgcn_mfma_f32_16x16x32_bf16(a0, b2, acc[0][2], 0, 0, 0);
            acc[0][3] = __builtin_amdgcn_mfma_f32_16x16x32_bf16(a0, b3, acc[0][3], 0, 0, 0);
            acc[1][0] = __builtin_amdgcn_mfma_f32_16x16x32_bf16(a1, b0, acc[1][0], 0, 0, 0);
            acc[1][1] = __builtin_amdgcn_mfma_f32_16x16x32_bf16(a1, b1, acc[1][1], 0, 0, 0);
            acc[1][2] = __builtin_amdgcn_mfma_f32_16x16x32_bf16(a1, b2, acc[1][2], 0, 0, 0);
            acc[1][3] = __builtin_amdgcn_mfma_f32_16x16x32_bf16(a1, b3, acc[1][3], 0, 0, 0);
        }
        __syncthreads();
    }
}

// ---------------- final GEMM, staged, fp32 out, nontemporal stores ----------------
template <int N>
__global__ __launch_bounds__(256) void gemm_k(const unsigned short* __restrict__ A,
                                              const unsigned short* __restrict__ W,
                                              const float* __restrict__ bias,
                                              float* __restrict__ outf) {
    __shared__ char smem[128 * 68 * 4];
    unsigned short* As = (unsigned short*)smem;
    unsigned short* Bs = As + 8192;
    float* sf = (float*)smem;
    const int tid = threadIdx.x, l = tid & 63, w = tid >> 6;
    const int ll = l & 15, lh = l >> 4;
    const int m0b = blockIdx.x * 128;
    const int n0 = blockIdx.y * 64;
    f32x4 acc[2][4] = {};
    staged_core256(A, m0b, W, n0, As, Bs, tid, acc);
#pragma unroll
    for (int mf = 0; mf < 2; mf++)
#pragma unroll
        for (int nf = 0; nf < 4; nf++)
#pragma unroll
            for (int r = 0; r < 4; r++) {
                int rowl = w * 32 + mf * 16 + lh * 4 + r;
                int col = nf * 16 + ll;
                sf[rowl * 68 + col] = acc[mf][nf][r] + bias[n0 + col];
            }
    __syncthreads();
#pragma unroll
    for (int p = 0; p < 8; p++) {
        int rowl = p * 16 + (tid >> 4);
        int col = (tid & 15) * 4;
        f32x4 v = *reinterpret_cast<const f32x4*>(&sf[rowl * 68 + col]);
        __builtin_nontemporal_store(v, reinterpret_cast<f32x4*>(outf + (size_t)(m0b + rowl) * N + n0 + col));
    }
}

// ---------------- fused gate + ip GEMM, staged, BM=128 (grid y: 0..3 gate, 4 = ip) ----------------
__global__ __launch_bounds__(256) void gateip_k(const unsigned short* __restrict__ xnb,
                                                const unsigned short* __restrict__ wg,
                                                const unsigned short* __restrict__ wip,
                                                const float* __restrict__ gbias, const float* __restrict__ ipb,
                                                const float* __restrict__ Bv, const float* __restrict__ bA,
                                                unsigned short* __restrict__ gB, float* __restrict__ u) {
    __shared__ char smem[128 * 68 * 4];
    unsigned short* As = (unsigned short*)smem;
    unsigned short* Bs = As + 8192;
    float* sf = (float*)smem;
    unsigned short* su = (unsigned short*)smem;
    const int tid = threadIdx.x, l = tid & 63, w = tid >> 6;
    const int ll = l & 15, lh = l >> 4;
    const int m0b = blockIdx.x * 128;
    const int y = blockIdx.y;
    const bool gate = (y < 4);
    const int n0 = gate ? y * 64 : 0;
    f32x4 acc[2][4] = {};
    staged_core256(xnb, m0b, gate ? wg : wip, n0, As, Bs, tid, acc);
    if (gate) {
#pragma unroll
        for (int mf = 0; mf < 2; mf++)
#pragma unroll
            for (int nf = 0; nf < 4; nf++)
#pragma unroll
                for (int r = 0; r < 4; r++) {
                    int rowl = w * 32 + mf * 16 + lh * 4 + r;
                    int col = nf * 16 + ll;
                    float v = acc[mf][nf][r] + gbias[n0 + col];
                    su[rowl * 72 + col] = f2bf(1.f / (1.f + __expf(-v)));
                }
        __syncthreads();
#pragma unroll
        for (int p = 0; p < 8; p++) {
            int rowl = p * 16 + (tid >> 4);
            int col = (tid & 15) * 4;
            ushort4 v = *reinterpret_cast<const ushort4*>(&su[rowl * 72 + col]);
            *reinterpret_cast<ushort4*>(gB + (size_t)(m0b + rowl) * HD + n0 + col) = v;
        }
    } else {
#pragma unroll
        for (int mf = 0; mf < 2; mf++)
#pragma unroll
            for (int nf = 0; nf < 4; nf++)
#pragma unroll
                for (int r = 0; r < 4; r++) {
                    int rowl = w * 32 + mf * 16 + lh * 4 + r;
                    int col = nf * 16 + ll;
                    float v = acc[mf][nf][r] + ipb[col];
                    sf[rowl * 68 + col] = Bv[col] * v + bA[col];
                }
        __syncthreads();
#pragma unroll
        for (int p = 0; p < 8; p++) {
            int rowl = p * 16 + (tid >> 4);
            int col = (tid & 15) * 4;
            int m = m0b + rowl;           // bt-order
            int t = m & 2047, b2 = m >> 11;
            float4 v = *reinterpret_cast<const float4*>(&sf[rowl * 68 + col]);
            *reinterpret_cast<float4*>(u + ((size_t)((t << 3) + b2)) * 64 + col) = v;
        }
    }
}

// ---------------- fused Cm + proj + blend + LN(next); phase-2 W staged ----------------
template <bool LAST>
__global__ __launch_bounds__(256) void post3_k(const unsigned short* __restrict__ Hs,
                                               const unsigned short* __restrict__ wc,
                                               const float* __restrict__ bC,
                                               const unsigned short* __restrict__ wp,
                                               const float* __restrict__ pb,
                                               const unsigned short* __restrict__ gB,
                                               unsigned short* __restrict__ xnb,
                                               unsigned short* __restrict__ hb,
                                               const float* __restrict__ lng2, const float* __restrict__ lnb2) {
    __shared__ unsigned short smem[16384 + 8192 + 32 * 264];  // Wp 32KB + ys 16KB + hnb 16.9KB
    unsigned short* Wp = smem;
    unsigned short* ys = smem + 16384;
    unsigned short* hnb = smem + 16384 + 8192;
    const int tid = threadIdx.x, l = tid & 63, w = tid >> 6;
    const int ll = l & 15, lh = l >> 4;
    const int mf = w >> 1, nh = w & 1;
    const int m0 = blockIdx.x * 32;          // tb-order
    const int r8 = l >> 3;
    const int csw = ((l & 7) ^ r8) * 8;
    const unsigned short* gwpR = wp + (size_t)(w * 8 + r8) * HD + csw;
    unsigned short* lwpR = Wp + (size_t)(w * 8) * 64 + l * 8;
    // phase 1: y = Hs @ Cm^T + bC (K=64), register path
    {
        short8 ha[2], cb[8][2];
        const unsigned short* Ap = Hs + (size_t)(m0 + mf * 16 + ll) * SD + lh * 8;
#pragma unroll
        for (int ks = 0; ks < 2; ks++)
            ha[ks] = *reinterpret_cast<const short8*>(Ap + ks * 32);
#pragma unroll
        for (int ks = 0; ks < 2; ks++)
#pragma unroll
            for (int j = 0; j < 8; j++)
                cb[j][ks] = *reinterpret_cast<const short8*>(wc + (size_t)((nh * 8 + j) * 16 + ll) * SD + ks * 32 + lh * 8);
        SBAR();
        f32x4 acc[8] = {};
#pragma unroll
        for (int ks = 0; ks < 2; ks++)
#pragma unroll
            for (int j = 0; j < 8; j++)
                acc[j] = __builtin_amdgcn_mfma_f32_16x16x32_bf16(ha[ks], cb[j][ks], acc[j], 0, 0, 0);
#pragma unroll
        for (int j = 0; j < 8; j++)
#pragma unroll
            for (int r = 0; r < 4; r++) {
                int rowl = mf * 16 + lh * 4 + r;
                int col = (nh * 8 + j) * 16 + ll;
                ys[swz(rowl, col, 256)] = f2bf(acc[j][r] + bC[col]);
            }
    }
    __syncthreads();
    // phase 2: y2 = y @ proj^T + pb (K=256), W staged via GLL (BK=64, 8-slot swizzle)
    {
        f32x4 acc2[8] = {};
        const int arow = mf * 16 + ll;
#pragma unroll
        for (int kb = 0; kb < 4; kb++) {
#pragma unroll
            for (int q = 0; q < 8; q++)
                GLL(gwpR + (size_t)(q * 32) * HD + kb * 64, lwpR + q * 32 * 64);
            __syncthreads();
#pragma unroll
            for (int ks = 0; ks < 2; ks++) {
                int c0 = kb * 64 + ks * 32 + lh * 8;
                short8 a = *reinterpret_cast<const short8*>(&ys[swz(arow, c0, 256)]);
                const int so = (((ks * 4 + lh) ^ (ll & 7)) * 8);
#pragma unroll
                for (int j = 0; j < 8; j++) {
                    short8 b = *reinterpret_cast<const short8*>(&Wp[(size_t)(nh * 128 + j * 16 + ll) * 64 + so]);
                    acc2[j] = __builtin_amdgcn_mfma_f32_16x16x32_bf16(a, b, acc2[j], 0, 0, 0);
                }
            }
            __syncthreads();
        }
#pragma unroll
        for (int j = 0; j < 8; j++)
#pragma unroll
            for (int r = 0; r < 4; r++) {
                int rowl = mf * 16 + lh * 4 + r;
                int col = (nh * 8 + j) * 16 + ll;
                hnb[rowl * 264 + col] = f2bf(acc2[j][r] + pb[col]);
            }
    }
    __syncthreads();
    // phase 3: blend + LN
#pragma unroll
    for (int q = 0; q < 8; q++) {
        int rowl = w * 8 + q;
        int m = m0 + rowl;               // tb-order
        int t = m >> 3, b2 = m & 7;
        size_t gidx = ((size_t)((b2 << 11) + t)) * HD + l * 4;
        ushort4 hv = *reinterpret_cast<const ushort4*>(hb + gidx);
        ushort4 gv = *reinterpret_cast<const ushort4*>(gB + gidx);
        ushort4 xv = *reinterpret_cast<const ushort4*>(xnb + gidx);
        ushort4 yv = *reinterpret_cast<const ushort4*>(&hnb[rowl * 264 + l * 4]);
        float g0 = bf2f(gv.x), g1 = bf2f(gv.y), g2 = bf2f(gv.z), g3 = bf2f(gv.w);
        float o0 = bf2f(hv.x) + g0 * bf2f(yv.x) + (1.f - g0) * bf2f(xv.x);
        float o1 = bf2f(hv.y) + g1 * bf2f(yv.y) + (1.f - g1) * bf2f(xv.y);
        float o2 = bf2f(hv.z) + g2 * bf2f(yv.z) + (1.f - g2) * bf2f(xv.z);
        float o3 = bf2f(hv.w) + g3 * bf2f(yv.w) + (1.f - g3) * bf2f(xv.w);
        ushort4 hbv;
        hbv.x = f2bf(o0); hbv.y = f2bf(o1); hbv.z = f2bf(o2); hbv.w = f2bf(o3);
        *reinterpret_cast<ushort4*>(hb + gidx) = hbv;
        if constexpr (!LAST) {
            float s = o0 + o1 + o2 + o3;
            float s2 = o0 * o0 + o1 * o1 + o2 * o2 + o3 * o3;
#pragma unroll
            for (int mm = 1; mm < 64; mm <<= 1) { s += __shfl_xor(s, mm); s2 += __shfl_xor(s2, mm); }
            float mean = s * (1.f / 256.f);
            float var = s2 * (1.f / 256.f) - mean * mean;
            float rstd = rsqrtf(var + 1e-5f);
            int c = l * 4;
            ushort4 xo;
            xo.x = f2bf((o0 - mean) * rstd * lng2[c + 0] + lnb2[c + 0]);
            xo.y = f2bf((o1 - mean) * rstd * lng2[c + 1] + lnb2[c + 1]);
            xo.z = f2bf((o2 - mean) * rstd * lng2[c + 2] + lnb2[c + 2]);
            xo.w = f2bf((o3 - mean) * rstd * lng2[c + 3] + lnb2[c + 3]);
            *reinterpret_cast<ushort4*>(xnb + gidx) = xo;
        }
    }
}

// ---------------- scan helpers ----------------
__device__ __forceinline__ void loadA64(const float* __restrict__ Af, int s, float* a) {
#pragma unroll
    for (int q = 0; q < 16; q++) {
        float4 v = reinterpret_cast<const float4*>(Af + s * 64)[q];
        a[q * 4 + 0] = v.x; a[q * 4 + 1] = v.y; a[q * 4 + 2] = v.z; a[q * 4 + 3] = v.w;
    }
}

__device__ __forceinline__ float step64(const float* a, float h, float uu) {
    float ac0 = uu, ac1 = 0.f, ac2 = 0.f, ac3 = 0.f;
#pragma unroll
    for (int k = 0; k < 64; k += 4) {
        float b0 = __int_as_float(__builtin_amdgcn_readlane(__float_as_int(h), k + 0));
        float b1 = __int_as_float(__builtin_amdgcn_readlane(__float_as_int(h), k + 1));
        float b2 = __int_as_float(__builtin_amdgcn_readlane(__float_as_int(h), k + 2));
        float b3 = __int_as_float(__builtin_amdgcn_readlane(__float_as_int(h), k + 3));
        ac0 = fmaf(b0, a[k + 0], ac0);
        ac1 = fmaf(b1, a[k + 1], ac1);
        ac2 = fmaf(b2, a[k + 2], ac2);
        ac3 = fmaf(b3, a[k + 3], ac3);
    }
    return (ac0 + ac1) + (ac2 + ac3);
}

__global__ __launch_bounds__(64) void scan_chunk_k(const float* __restrict__ Af,
                                                   const float* __restrict__ u,
                                                   float* __restrict__ Slast) {
    const int c = blockIdx.x >> 3, b = blockIdx.x & 7;
    const int s = threadIdx.x;
    float a[64];
    loadA64(Af, s, a);
    const float* up = u + (c * CLEN) * 512 + b * 64 + s;
    float uv[CLEN];
#pragma unroll
    for (int i = 0; i < CLEN; i++) uv[i] = up[i * 512];
    float h = 0.f;
#pragma unroll
    for (int i = 0; i < CLEN; i++) h = step64(a, h, uv[i]);
    Slast[blockIdx.x * 64 + s] = h;
}

__global__ __launch_bounds__(64) void replay_k(const float* __restrict__ Af,
                                               const float* __restrict__ Apow,
                                               const float* __restrict__ u,
                                               const float* __restrict__ Slast,
                                               unsigned short* __restrict__ Hs,
                                               int* __restrict__ flag) {
    const int c = blockIdx.x >> 3, b = blockIdx.x & 7;
    const int s = threadIdx.x;
    float a[64];
    float carry = 0.f;
    if (c > 0) {
        loadA64(Apow, s, a);
        for (int j = 0; j < c; j++) {
            float sl = Slast[(j * 8 + b) * 64 + s];
            carry = step64(a, carry, sl);
        }
    }
    loadA64(Af, s, a);
    const float* up = u + (c * CLEN) * 512 + b * 64 + s;
    float uv[CLEN];
#pragma unroll
    for (int i = 0; i < CLEN; i++) uv[i] = up[i * 512];
    float h = carry;
    unsigned short* hp = Hs + (c * CLEN) * 512 + b * 64 + s;
    bool bad = false;
#pragma unroll
    for (int i = 0; i < CLEN; i++) {
        h = step64(a, h, uv[i]);
        bad |= (fabsf(h) > 10.f);
        hp[i * 512] = f2bf(h);
    }
    if (__any(bad ? 1 : 0)) {
        if (s == 0) atomicOr(flag, 1);
    }
}

__global__ __launch_bounds__(64) void scan_seq_k(const float* __restrict__ Af,
                                                 const float* __restrict__ u,
                                                 unsigned short* __restrict__ Hs,
                                                 const int* __restrict__ flag) {
    if (*flag == 0) return;
    const int b = blockIdx.x;
    const int s = threadIdx.x;
    float a[64];
    loadA64(Af, s, a);
    float h = 0.f;
    for (int t = 0; t < T_LEN; t++) {
        float uu = u[((t << 3) + b) * 64 + s];
        float hp = step64(a, h, uu);
        h = fminf(fmaxf(hp, -10.f), 10.f);
        Hs[((t << 3) + b) * 64 + s] = f2bf(h);
    }
}

// ---------------- launch ----------------
extern "C" void kernel_launch(void* const* d_in, const int* in_sizes, int n_in,
                              void* d_out, int out_size, void* d_ws, size_t ws_size,
                              hipStream_t stream) {
    const float* x    = (const float*)d_in[0];
    const float* inw  = (const float*)d_in[1];
    const float* inb  = (const float*)d_in[2];
    const float* lng  = (const float*)d_in[3];
    const float* lnb  = (const float*)d_in[4];
    const float* ipw  = (const float*)d_in[5];
    const float* ipb  = (const float*)d_in[6];
    const float* Amat = (const float*)d_in[7];
    const float* Bv   = (const float*)d_in[8];
    const float* Cm   = (const float*)d_in[9];
    const float* bA   = (const float*)d_in[10];
    const float* bC   = (const float*)d_in[11];
    const float* gw   = (const float*)d_in[12];
    const float* gbia = (const float*)d_in[13];
    const float* pw   = (const float*)d_in[14];
    const float* pb   = (const float*)d_in[15];
    const float* ow   = (const float*)d_in[16];
    const float* ob   = (const float*)d_in[17];

    char* ws = (char*)d_ws;
    float*          u  = (float*)(ws + 0);                   // 4 MB
    unsigned short* Hs = (unsigned short*)(ws + 4194304);    // 2 MB
    unsigned short* hb = (unsigned short*)(ws + 14680064);   // 8 MB (bf16 residual)
    unsigned short* wb = (unsigned short*)(ws + 25165824);   // 2 MB
    unsigned short* xnb = (unsigned short*)(ws + 44040192);  // 8 MB
    unsigned short* gB  = (unsigned short*)(ws + 52428800);  // 8 MB

    char* sc = (char*)d_out;   // small scratch; fully overwritten by final GEMM
    float* Apow  = (float*)(sc + 0);          // 64 KB: [4][64][64] (A^64)
    float* Slast = (float*)(sc + 65536);      // 64 KB
    int*   flag  = (int*)(sc + 196608);       // 16 B

    const unsigned short* w_in = wb + 0;
    const unsigned short* w_ip = wb + 196608;
    const unsigned short* w_g  = wb + 262144;
    const unsigned short* w_p  = wb + 524288;
    const unsigned short* w_c  = wb + 786432;
    const unsigned short* w_o  = wb + 851968;

    hipMemsetAsync(flag, 0, 16, stream);
    cvt_w_k<<<4096, 256, 0, stream>>>(inw, ipw, gw, pw, Cm, ow, wb);
    matpow_k<<<4, 256, 0, stream>>>(Amat, Apow);

    in_ln_k<<<512, 256, 0, stream>>>(x, w_in, inb, lng, lnb, hb, xnb);
    for (int i = 0; i < 4; i++) {
        gateip_k<<<dim3(128, 5), 256, 0, stream>>>(xnb, w_g + i * 65536, w_ip + i * 16384,
                                                   gbia + i * HD, ipb + i * SD,
                                                   Bv + i * SD, bA + i * SD, gB, u);
        scan_chunk_k<<<256, 64, 0, stream>>>(Amat + i * 4096, u, Slast);
        replay_k<<<256, 64, 0, stream>>>(Amat + i * 4096, Apow + i * 4096, u, Slast, Hs, flag + i);
        scan_seq_k<<<8, 64, 0, stream>>>(Amat + i * 4096, u, Hs, flag + i);
        if (i < 3)
            post3_k<false><<<512, 256, 0, stream>>>(Hs, w_c + i * 16384, bC + i * HD,
                                                    w_p + i * 65536, pb + i * HD, gB, xnb, hb,
                                                    lng + (i + 1) * HD, lnb + (i + 1) * HD);
        else
            post3_k<true><<<512, 256, 0, stream>>>(Hs, w_c + i * 16384, bC + i * HD,
                                                   w_p + i * 65536, pb + i * HD, gB, xnb, hb,
                                                   lng, lnb);
    }
    gemm_k<DOUT><<<dim3(128, 12), 256, 0, stream>>>(hb, w_o, ob, (float*)d_out);
}

// Round 21
// 349.257 us; speedup vs baseline: 1.1701x; 1.0527x over previous
//
#include <hip/hip_runtime.h>

typedef float f32x4 __attribute__((ext_vector_type(4)));
typedef short short8 __attribute__((ext_vector_type(8)));

#define T_LEN 2048
#define HD 256
#define SD 64
#define DIN 768
#define DOUT 768
#define NCHUNK 64
#define CLEN 32

#define SBAR() __builtin_amdgcn_sched_barrier(0)

__device__ __forceinline__ unsigned short f2bf(float f) {
    unsigned int u = __float_as_uint(f);
    unsigned int r = u + 0x7FFFu + ((u >> 16) & 1u);
    return (unsigned short)(r >> 16);
}
__device__ __forceinline__ float bf2f(unsigned short h) {
    return __uint_as_float(((unsigned int)h) << 16);
}
__device__ __forceinline__ int swz(int row, int col, int stride) {
    return row * stride + (col ^ ((row & 7) << 3));
}
#define GLL(gp, lp) __builtin_amdgcn_global_load_lds( \
    (const __attribute__((address_space(1))) void*)(gp), \
    (__attribute__((address_space(3))) void*)(lp), 16, 0, 0)

// ---------------- weight conversion ----------------
__global__ __launch_bounds__(256) void cvt_w_k(const float* __restrict__ s0, const float* __restrict__ s1,
                                               const float* __restrict__ s2, const float* __restrict__ s3,
                                               const float* __restrict__ s4, const float* __restrict__ s5,
                                               unsigned short* __restrict__ d) {
    int i = blockIdx.x * 256 + threadIdx.x;
    if (i >= 1048576) return;
    float v;
    if (i < 196608)      v = s0[i];
    else if (i < 262144) v = s1[i - 196608];
    else if (i < 524288) v = s2[i - 262144];
    else if (i < 786432) v = s3[i - 524288];
    else if (i < 851968) v = s4[i - 786432];
    else                 v = s5[i - 851968];
    d[i] = f2bf(v);
}

// ---------------- A^32 via bf16-split MFMA (5 squarings) ----------------
__global__ __launch_bounds__(256) void matpow_k(const float* __restrict__ A, float* __restrict__ Apow) {
    __shared__ unsigned short Mh[4096], Ml[4096], MhT[4096], MlT[4096];
    const int l = blockIdx.x, tid = threadIdx.x;
    const int w = tid >> 6, ln = tid & 63, ll = ln & 15, lh = ln >> 4;
    const float* src = A + l * 4096;
    for (int i = tid; i < 4096; i += 256) {
        float v = src[i];
        unsigned short hi = f2bf(v);
        unsigned short lo = f2bf(v - bf2f(hi));
        int r = i >> 6, c = i & 63;
        Mh[swz(r, c, 64)] = hi;  Ml[swz(r, c, 64)] = lo;
        MhT[swz(c, r, 64)] = hi; MlT[swz(c, r, 64)] = lo;
    }
    __syncthreads();
    for (int it = 0; it < 5; it++) {   // A^(2^5) = A^32
        f32x4 acc[4] = {};
#pragma unroll
        for (int ks = 0; ks < 2; ks++) {
            int ar = w * 16 + ll, c0 = ks * 32 + lh * 8;
            short8 ah = *reinterpret_cast<const short8*>(&Mh[swz(ar, c0, 64)]);
            short8 al = *reinterpret_cast<const short8*>(&Ml[swz(ar, c0, 64)]);
#pragma unroll
            for (int nf = 0; nf < 4; nf++) {
                int br = nf * 16 + ll;
                short8 bh = *reinterpret_cast<const short8*>(&MhT[swz(br, c0, 64)]);
                short8 bl = *reinterpret_cast<const short8*>(&MlT[swz(br, c0, 64)]);
                acc[nf] = __builtin_amdgcn_mfma_f32_16x16x32_bf16(ah, bh, acc[nf], 0, 0, 0);
                acc[nf] = __builtin_amdgcn_mfma_f32_16x16x32_bf16(ah, bl, acc[nf], 0, 0, 0);
                acc[nf] = __builtin_amdgcn_mfma_f32_16x16x32_bf16(al, bh, acc[nf], 0, 0, 0);
            }
        }
        __syncthreads();
#pragma unroll
        for (int nf = 0; nf < 4; nf++)
#pragma unroll
            for (int r = 0; r < 4; r++) {
                float v = acc[nf][r];
                int row = w * 16 + lh * 4 + r, col = nf * 16 + ll;
                unsigned short hi = f2bf(v);
                unsigned short lo = f2bf(v - bf2f(hi));
                Mh[swz(row, col, 64)] = hi;  Ml[swz(row, col, 64)] = lo;
                MhT[swz(col, row, 64)] = hi; MlT[swz(col, row, 64)] = lo;
            }
        __syncthreads();
    }
    for (int i = tid; i < 4096; i += 256) {
        int r = i >> 6, c = i & 63;
        Apow[l * 4096 + i] = bf2f(Mh[swz(r, c, 64)]) + bf2f(Ml[swz(r, c, 64)]);
    }
}

// ---------------- fused in-proj + LN, BM=32, BK=64, W staged (8-slot swizzle) ----------------
__global__ __launch_bounds__(256) void in_ln_k(const float* __restrict__ x,
                                               const unsigned short* __restrict__ w_in,
                                               const float* __restrict__ inb,
                                               const float* __restrict__ lng, const float* __restrict__ lnb,
                                               unsigned short* __restrict__ hb, unsigned short* __restrict__ xnb) {
    __shared__ unsigned short smem[16384 + 32 * 264];   // Ws 32KB + hnb 16.9KB
    unsigned short* Ws = smem;
    unsigned short* hnb = smem + 16384;
    const int tid = threadIdx.x, l = tid & 63, w = tid >> 6;
    const int ll = l & 15, lh = l >> 4;
    const int mf = w >> 1, nh = w & 1;
    const int m0 = blockIdx.x * 32;
    const int r8 = l >> 3;
    const int csw = ((l & 7) ^ r8) * 8;
    const float* ap = x + (size_t)(m0 + mf * 16 + ll) * DIN + lh * 8;
    const unsigned short* gwR = w_in + (size_t)(w * 8 + r8) * DIN + csw;
    unsigned short* lwR = Ws + (size_t)(w * 8) * 64 + l * 8;
    f32x4 acc[8] = {};
    for (int k0 = 0; k0 < DIN; k0 += 64) {
#pragma unroll
        for (int q = 0; q < 8; q++)
            GLL(gwR + (size_t)(q * 32) * DIN + k0, lwR + q * 32 * 64);
        short8 af[2];
#pragma unroll
        for (int ks = 0; ks < 2; ks++) {
            float4 a0 = *reinterpret_cast<const float4*>(ap + k0 + ks * 32);
            float4 a1 = *reinterpret_cast<const float4*>(ap + k0 + ks * 32 + 4);
            short8 t;
            t[0] = (short)f2bf(a0.x); t[1] = (short)f2bf(a0.y);
            t[2] = (short)f2bf(a0.z); t[3] = (short)f2bf(a0.w);
            t[4] = (short)f2bf(a1.x); t[5] = (short)f2bf(a1.y);
            t[6] = (short)f2bf(a1.z); t[7] = (short)f2bf(a1.w);
            af[ks] = t;
        }
        __syncthreads();
#pragma unroll
        for (int ks = 0; ks < 2; ks++) {
            const int so = (((ks * 4 + lh) ^ (ll & 7)) * 8);
#pragma unroll
            for (int j = 0; j < 8; j++) {
                short8 b = *reinterpret_cast<const short8*>(&Ws[(size_t)(nh * 128 + j * 16 + ll) * 64 + so]);
                acc[j] = __builtin_amdgcn_mfma_f32_16x16x32_bf16(af[ks], b, acc[j], 0, 0, 0);
            }
        }
        __syncthreads();
    }
#pragma unroll
    for (int j = 0; j < 8; j++)
#pragma unroll
        for (int r = 0; r < 4; r++) {
            int rowl = mf * 16 + lh * 4 + r;
            int col = nh * 128 + j * 16 + ll;
            hnb[rowl * 264 + col] = f2bf(acc[j][r] + inb[col]);
        }
    __syncthreads();
#pragma unroll
    for (int q = 0; q < 8; q++) {
        int rowl = w * 8 + q;
        size_t gidx = (size_t)(m0 + rowl) * HD + l * 4;
        ushort4 hv = *reinterpret_cast<const ushort4*>(&hnb[rowl * 264 + l * 4]);
        float o0 = bf2f(hv.x), o1 = bf2f(hv.y), o2 = bf2f(hv.z), o3 = bf2f(hv.w);
        float s = o0 + o1 + o2 + o3;
        float s2 = o0 * o0 + o1 * o1 + o2 * o2 + o3 * o3;
#pragma unroll
        for (int mm = 1; mm < 64; mm <<= 1) { s += __shfl_xor(s, mm); s2 += __shfl_xor(s2, mm); }
        float mean = s * (1.f / 256.f);
        float var = s2 * (1.f / 256.f) - mean * mean;
        float rstd = rsqrtf(var + 1e-5f);
        int c = l * 4;
        *reinterpret_cast<ushort4*>(hb + gidx) = hv;
        ushort4 xo;
        xo.x = f2bf((o0 - mean) * rstd * lng[c + 0] + lnb[c + 0]);
        xo.y = f2bf((o1 - mean) * rstd * lng[c + 1] + lnb[c + 1]);
        xo.z = f2bf((o2 - mean) * rstd * lng[c + 2] + lnb[c + 2]);
        xo.w = f2bf((o3 - mean) * rstd * lng[c + 3] + lnb[c + 3]);
        *reinterpret_cast<ushort4*>(xnb + gidx) = xo;
    }
}

// ---------------- staged GEMM core, K=256, BK=64 (8-slot swizzle) ----------------
__device__ __forceinline__ void staged_core256(const unsigned short* __restrict__ A, int m0b,
                                               const unsigned short* __restrict__ W, int n0,
                                               unsigned short* As, unsigned short* Bs,
                                               int tid, f32x4 (*acc)[4]) {
    const int l = tid & 63, w = tid >> 6;
    const int ll = l & 15, lh = l >> 4;
    const int r8 = l >> 3;
    const int csw = ((l & 7) ^ r8) * 8;
    const unsigned short* gaR = A + (size_t)(m0b + w * 8 + r8) * 256 + csw;
    const unsigned short* gbR = W + (size_t)(n0 + w * 8 + r8) * 256 + csw;
    unsigned short* laR = As + (size_t)(w * 8) * 64 + l * 8;
    unsigned short* lbR = Bs + (size_t)(w * 8) * 64 + l * 8;
#pragma unroll
    for (int k0 = 0; k0 < 256; k0 += 64) {
#pragma unroll
        for (int q = 0; q < 4; q++)
            GLL(gaR + (size_t)(q * 32) * 256 + k0, laR + q * 32 * 64);
#pragma unroll
        for (int q = 0; q < 2; q++)
            GLL(gbR + (size_t)(q * 32) * 256 + k0, lbR + q * 32 * 64);
        __syncthreads();
#pragma unroll
        for (int ks = 0; ks < 2; ks++) {
            const int so = (((ks * 4 + lh) ^ (ll & 7)) * 8);
            short8 a0 = *reinterpret_cast<const short8*>(&As[(size_t)(w * 32 + ll) * 64 + so]);
            short8 a1 = *reinterpret_cast<const short8*>(&As[(size_t)(w * 32 + 16 + ll) * 64 + so]);
            short8 b0 = *reinterpret_cast<const short8*>(&Bs[(size_t)(ll) * 64 + so]);
            short8 b1 = *reinterpret_cast<const short8*>(&Bs[(size_t)(16 + ll) * 64 + so]);
            short8 b2 = *reinterpret_cast<const short8*>(&Bs[(size_t)(32 + ll) * 64 + so]);
            short8 b3 = *reinterpret_cast<const short8*>(&Bs[(size_t)(48 + ll) * 64 + so]);
            acc[0][0] = __builtin_amdgcn_mfma_f32_16x16x32_bf16(a0, b0, acc[0][0], 0, 0, 0);
            acc[0][1] = __builtin_amdgcn_mfma_f32_16x16x32_bf16(a0, b1, acc[0][1], 0, 0, 0);
            acc[0][2] = __builtin_amdgcn_mfma_f32_16x16x32_bf16(a0, b2, acc[0][2], 0, 0, 0);
            acc[0][3] = __builtin_amdgcn_mfma_f32_16x16x32_bf16(a0, b3, acc[0][3], 0, 0, 0);
            acc[1][0] = __builtin_amdgcn_mfma_f32_16x16x32_bf16(a1, b0, acc[1][0], 0, 0, 0);
            acc[1][1] = __builtin_amdgcn_mfma_f32_16x16x32_bf16(a1, b1, acc[1][1], 0, 0, 0);
            acc[1][2] = __builtin_amdgcn_mfma_f32_16x16x32_bf16(a1, b2, acc[1][2], 0, 0, 0);
            acc[1][3] = __builtin_amdgcn_mfma_f32_16x16x32_bf16(a1, b3, acc[1][3], 0, 0, 0);
        }
        __syncthreads();
    }
}

// ---------------- final GEMM, staged, fp32 out, nontemporal stores ----------------
template <int N>
__global__ __launch_bounds__(256) void gemm_k(const unsigned short* __restrict__ A,
                                              const unsigned short* __restrict__ W,
                                              const float* __restrict__ bias,
                                              float* __restrict__ outf) {
    __shared__ char smem[128 * 68 * 4];
    unsigned short* As = (unsigned short*)smem;
    unsigned short* Bs = As + 8192;
    float* sf = (float*)smem;
    const int tid = threadIdx.x, l = tid & 63, w = tid >> 6;
    const int ll = l & 15, lh = l >> 4;
    const int m0b = blockIdx.x * 128;
    const int n0 = blockIdx.y * 64;
    f32x4 acc[2][4] = {};
    staged_core256(A, m0b, W, n0, As, Bs, tid, acc);
#pragma unroll
    for (int mf = 0; mf < 2; mf++)
#pragma unroll
        for (int nf = 0; nf < 4; nf++)
#pragma unroll
            for (int r = 0; r < 4; r++) {
                int rowl = w * 32 + mf * 16 + lh * 4 + r;
                int col = nf * 16 + ll;
                sf[rowl * 68 + col] = acc[mf][nf][r] + bias[n0 + col];
            }
    __syncthreads();
#pragma unroll
    for (int p = 0; p < 8; p++) {
        int rowl = p * 16 + (tid >> 4);
        int col = (tid & 15) * 4;
        f32x4 v = *reinterpret_cast<const f32x4*>(&sf[rowl * 68 + col]);
        __builtin_nontemporal_store(v, reinterpret_cast<f32x4*>(outf + (size_t)(m0b + rowl) * N + n0 + col));
    }
}

// ---------------- fused gate + ip GEMM, staged, BM=128 (grid y: 0..3 gate, 4 = ip) ----------------
__global__ __launch_bounds__(256) void gateip_k(const unsigned short* __restrict__ xnb,
                                                const unsigned short* __restrict__ wg,
                                                const unsigned short* __restrict__ wip,
                                                const float* __restrict__ gbias, const float* __restrict__ ipb,
                                                const float* __restrict__ Bv, const float* __restrict__ bA,
                                                unsigned short* __restrict__ gB, float* __restrict__ u) {
    __shared__ char smem[128 * 68 * 4];
    unsigned short* As = (unsigned short*)smem;
    unsigned short* Bs = As + 8192;
    float* sf = (float*)smem;
    unsigned short* su = (unsigned short*)smem;
    const int tid = threadIdx.x, l = tid & 63, w = tid >> 6;
    const int ll = l & 15, lh = l >> 4;
    const int m0b = blockIdx.x * 128;
    const int y = blockIdx.y;
    const bool gate = (y < 4);
    const int n0 = gate ? y * 64 : 0;
    f32x4 acc[2][4] = {};
    staged_core256(xnb, m0b, gate ? wg : wip, n0, As, Bs, tid, acc);
    if (gate) {
#pragma unroll
        for (int mf = 0; mf < 2; mf++)
#pragma unroll
            for (int nf = 0; nf < 4; nf++)
#pragma unroll
                for (int r = 0; r < 4; r++) {
                    int rowl = w * 32 + mf * 16 + lh * 4 + r;
                    int col = nf * 16 + ll;
                    float v = acc[mf][nf][r] + gbias[n0 + col];
                    su[rowl * 72 + col] = f2bf(1.f / (1.f + __expf(-v)));
                }
        __syncthreads();
#pragma unroll
        for (int p = 0; p < 8; p++) {
            int rowl = p * 16 + (tid >> 4);
            int col = (tid & 15) * 4;
            ushort4 v = *reinterpret_cast<const ushort4*>(&su[rowl * 72 + col]);
            *reinterpret_cast<ushort4*>(gB + (size_t)(m0b + rowl) * HD + n0 + col) = v;
        }
    } else {
#pragma unroll
        for (int mf = 0; mf < 2; mf++)
#pragma unroll
            for (int nf = 0; nf < 4; nf++)
#pragma unroll
                for (int r = 0; r < 4; r++) {
                    int rowl = w * 32 + mf * 16 + lh * 4 + r;
                    int col = nf * 16 + ll;
                    float v = acc[mf][nf][r] + ipb[col];
                    sf[rowl * 68 + col] = Bv[col] * v + bA[col];
                }
        __syncthreads();
#pragma unroll
        for (int p = 0; p < 8; p++) {
            int rowl = p * 16 + (tid >> 4);
            int col = (tid & 15) * 4;
            int m = m0b + rowl;           // bt-order
            int t = m & 2047, b2 = m >> 11;
            float4 v = *reinterpret_cast<const float4*>(&sf[rowl * 68 + col]);
            *reinterpret_cast<float4*>(u + ((size_t)((t << 3) + b2)) * 64 + col) = v;
        }
    }
}

// ---------------- fused Cm + proj + blend + LN(next); phase-2 W staged ----------------
template <bool LAST>
__global__ __launch_bounds__(256) void post3_k(const unsigned short* __restrict__ Hs,
                                               const unsigned short* __restrict__ wc,
                                               const float* __restrict__ bC,
                                               const unsigned short* __restrict__ wp,
                                               const float* __restrict__ pb,
                                               const unsigned short* __restrict__ gB,
                                               unsigned short* __restrict__ xnb,
                                               unsigned short* __restrict__ hb,
                                               const float* __restrict__ lng2, const float* __restrict__ lnb2) {
    __shared__ unsigned short smem[16384 + 8192 + 32 * 264];  // Wp 32KB + ys 16KB + hnb 16.9KB
    unsigned short* Wp = smem;
    unsigned short* ys = smem + 16384;
    unsigned short* hnb = smem + 16384 + 8192;
    const int tid = threadIdx.x, l = tid & 63, w = tid >> 6;
    const int ll = l & 15, lh = l >> 4;
    const int mf = w >> 1, nh = w & 1;
    const int m0 = blockIdx.x * 32;          // tb-order
    const int r8 = l >> 3;
    const int csw = ((l & 7) ^ r8) * 8;
    const unsigned short* gwpR = wp + (size_t)(w * 8 + r8) * HD + csw;
    unsigned short* lwpR = Wp + (size_t)(w * 8) * 64 + l * 8;
    {
        short8 ha[2], cb[8][2];
        const unsigned short* Ap = Hs + (size_t)(m0 + mf * 16 + ll) * SD + lh * 8;
#pragma unroll
        for (int ks = 0; ks < 2; ks++)
            ha[ks] = *reinterpret_cast<const short8*>(Ap + ks * 32);
#pragma unroll
        for (int ks = 0; ks < 2; ks++)
#pragma unroll
            for (int j = 0; j < 8; j++)
                cb[j][ks] = *reinterpret_cast<const short8*>(wc + (size_t)((nh * 8 + j) * 16 + ll) * SD + ks * 32 + lh * 8);
        SBAR();
        f32x4 acc[8] = {};
#pragma unroll
        for (int ks = 0; ks < 2; ks++)
#pragma unroll
            for (int j = 0; j < 8; j++)
                acc[j] = __builtin_amdgcn_mfma_f32_16x16x32_bf16(ha[ks], cb[j][ks], acc[j], 0, 0, 0);
#pragma unroll
        for (int j = 0; j < 8; j++)
#pragma unroll
            for (int r = 0; r < 4; r++) {
                int rowl = mf * 16 + lh * 4 + r;
                int col = (nh * 8 + j) * 16 + ll;
                ys[swz(rowl, col, 256)] = f2bf(acc[j][r] + bC[col]);
            }
    }
    __syncthreads();
    {
        f32x4 acc2[8] = {};
        const int arow = mf * 16 + ll;
#pragma unroll
        for (int kb = 0; kb < 4; kb++) {
#pragma unroll
            for (int q = 0; q < 8; q++)
                GLL(gwpR + (size_t)(q * 32) * HD + kb * 64, lwpR + q * 32 * 64);
            __syncthreads();
#pragma unroll
            for (int ks = 0; ks < 2; ks++) {
                int c0 = kb * 64 + ks * 32 + lh * 8;
                short8 a = *reinterpret_cast<const short8*>(&ys[swz(arow, c0, 256)]);
                const int so = (((ks * 4 + lh) ^ (ll & 7)) * 8);
#pragma unroll
                for (int j = 0; j < 8; j++) {
                    short8 b = *reinterpret_cast<const short8*>(&Wp[(size_t)(nh * 128 + j * 16 + ll) * 64 + so]);
                    acc2[j] = __builtin_amdgcn_mfma_f32_16x16x32_bf16(a, b, acc2[j], 0, 0, 0);
                }
            }
            __syncthreads();
        }
#pragma unroll
        for (int j = 0; j < 8; j++)
#pragma unroll
            for (int r = 0; r < 4; r++) {
                int rowl = mf * 16 + lh * 4 + r;
                int col = (nh * 8 + j) * 16 + ll;
                hnb[rowl * 264 + col] = f2bf(acc2[j][r] + pb[col]);
            }
    }
    __syncthreads();
#pragma unroll
    for (int q = 0; q < 8; q++) {
        int rowl = w * 8 + q;
        int m = m0 + rowl;               // tb-order
        int t = m >> 3, b2 = m & 7;
        size_t gidx = ((size_t)((b2 << 11) + t)) * HD + l * 4;
        ushort4 hv = *reinterpret_cast<const ushort4*>(hb + gidx);
        ushort4 gv = *reinterpret_cast<const ushort4*>(gB + gidx);
        ushort4 xv = *reinterpret_cast<const ushort4*>(xnb + gidx);
        ushort4 yv = *reinterpret_cast<const ushort4*>(&hnb[rowl * 264 + l * 4]);
        float g0 = bf2f(gv.x), g1 = bf2f(gv.y), g2 = bf2f(gv.z), g3 = bf2f(gv.w);
        float o0 = bf2f(hv.x) + g0 * bf2f(yv.x) + (1.f - g0) * bf2f(xv.x);
        float o1 = bf2f(hv.y) + g1 * bf2f(yv.y) + (1.f - g1) * bf2f(xv.y);
        float o2 = bf2f(hv.z) + g2 * bf2f(yv.z) + (1.f - g2) * bf2f(xv.z);
        float o3 = bf2f(hv.w) + g3 * bf2f(yv.w) + (1.f - g3) * bf2f(xv.w);
        ushort4 hbv;
        hbv.x = f2bf(o0); hbv.y = f2bf(o1); hbv.z = f2bf(o2); hbv.w = f2bf(o3);
        *reinterpret_cast<ushort4*>(hb + gidx) = hbv;
        if constexpr (!LAST) {
            float s = o0 + o1 + o2 + o3;
            float s2 = o0 * o0 + o1 * o1 + o2 * o2 + o3 * o3;
#pragma unroll
            for (int mm = 1; mm < 64; mm <<= 1) { s += __shfl_xor(s, mm); s2 += __shfl_xor(s2, mm); }
            float mean = s * (1.f / 256.f);
            float var = s2 * (1.f / 256.f) - mean * mean;
            float rstd = rsqrtf(var + 1e-5f);
            int c = l * 4;
            ushort4 xo;
            xo.x = f2bf((o0 - mean) * rstd * lng2[c + 0] + lnb2[c + 0]);
            xo.y = f2bf((o1 - mean) * rstd * lng2[c + 1] + lnb2[c + 1]);
            xo.z = f2bf((o2 - mean) * rstd * lng2[c + 2] + lnb2[c + 2]);
            xo.w = f2bf((o3 - mean) * rstd * lng2[c + 3] + lnb2[c + 3]);
            *reinterpret_cast<ushort4*>(xnb + gidx) = xo;
        }
    }
}

// ---------------- scan helpers ----------------
__device__ __forceinline__ void loadA64(const float* __restrict__ Af, int s, float* a) {
#pragma unroll
    for (int q = 0; q < 16; q++) {
        float4 v = reinterpret_cast<const float4*>(Af + s * 64)[q];
        a[q * 4 + 0] = v.x; a[q * 4 + 1] = v.y; a[q * 4 + 2] = v.z; a[q * 4 + 3] = v.w;
    }
}

__device__ __forceinline__ float step64(const float* a, float h, float uu) {
    float ac0 = uu, ac1 = 0.f, ac2 = 0.f, ac3 = 0.f;
#pragma unroll
    for (int k = 0; k < 64; k += 4) {
        float b0 = __int_as_float(__builtin_amdgcn_readlane(__float_as_int(h), k + 0));
        float b1 = __int_as_float(__builtin_amdgcn_readlane(__float_as_int(h), k + 1));
        float b2 = __int_as_float(__builtin_amdgcn_readlane(__float_as_int(h), k + 2));
        float b3 = __int_as_float(__builtin_amdgcn_readlane(__float_as_int(h), k + 3));
        ac0 = fmaf(b0, a[k + 0], ac0);
        ac1 = fmaf(b1, a[k + 1], ac1);
        ac2 = fmaf(b2, a[k + 2], ac2);
        ac3 = fmaf(b3, a[k + 3], ac3);
    }
    return (ac0 + ac1) + (ac2 + ac3);
}

__global__ __launch_bounds__(64) void scan_chunk_k(const float* __restrict__ Af,
                                                   const float* __restrict__ u,
                                                   float* __restrict__ Slast) {
    const int c = blockIdx.x >> 3, b = blockIdx.x & 7;
    const int s = threadIdx.x;
    float a[64];
    loadA64(Af, s, a);
    const float* up = u + (size_t)(c * CLEN) * 512 + b * 64 + s;
    float uv[CLEN];
#pragma unroll
    for (int i = 0; i < CLEN; i++) uv[i] = up[(size_t)i * 512];
    float h = 0.f;
#pragma unroll
    for (int i = 0; i < CLEN; i++) h = step64(a, h, uv[i]);
    Slast[blockIdx.x * 64 + s] = h;
}

// replay with in-block carry recomputation (A^32 powers)
__global__ __launch_bounds__(64) void replay_k(const float* __restrict__ Af,
                                               const float* __restrict__ Apow,
                                               const float* __restrict__ u,
                                               const float* __restrict__ Slast,
                                               unsigned short* __restrict__ Hs,
                                               int* __restrict__ flag) {
    const int c = blockIdx.x >> 3, b = blockIdx.x & 7;
    const int s = threadIdx.x;
    float a[64];
    float carry = 0.f;
    if (c > 0) {
        loadA64(Apow, s, a);
        for (int j = 0; j < c; j++) {
            float sl = Slast[(j * 8 + b) * 64 + s];
            carry = step64(a, carry, sl);
        }
    }
    loadA64(Af, s, a);
    const float* up = u + (size_t)(c * CLEN) * 512 + b * 64 + s;
    float uv[CLEN];
#pragma unroll
    for (int i = 0; i < CLEN; i++) uv[i] = up[(size_t)i * 512];
    float h = carry;
    unsigned short* hp = Hs + (size_t)(c * CLEN) * 512 + b * 64 + s;
    bool bad = false;
#pragma unroll
    for (int i = 0; i < CLEN; i++) {
        h = step64(a, h, uv[i]);
        bad |= (fabsf(h) > 10.f);
        hp[(size_t)i * 512] = f2bf(h);
    }
    if (__any(bad ? 1 : 0)) {
        if (s == 0) atomicOr(flag, 1);
    }
}

__global__ __launch_bounds__(64) void scan_seq_k(const float* __restrict__ Af,
                                                 const float* __restrict__ u,
                                                 unsigned short* __restrict__ Hs,
                                                 const int* __restrict__ flag) {
    if (*flag == 0) return;
    const int b = blockIdx.x;
    const int s = threadIdx.x;
    float a[64];
    loadA64(Af, s, a);
    float h = 0.f;
    for (int t = 0; t < T_LEN; t++) {
        float uu = u[((size_t)(t << 3) + b) * 64 + s];
        float hp = step64(a, h, uu);
        h = fminf(fmaxf(hp, -10.f), 10.f);
        Hs[((size_t)(t << 3) + b) * 64 + s] = f2bf(h);
    }
}

// ---------------- launch ----------------
extern "C" void kernel_launch(void* const* d_in, const int* in_sizes, int n_in,
                              void* d_out, int out_size, void* d_ws, size_t ws_size,
                              hipStream_t stream) {
    const float* x    = (const float*)d_in[0];
    const float* inw  = (const float*)d_in[1];
    const float* inb  = (const float*)d_in[2];
    const float* lng  = (const float*)d_in[3];
    const float* lnb  = (const float*)d_in[4];
    const float* ipw  = (const float*)d_in[5];
    const float* ipb  = (const float*)d_in[6];
    const float* Amat = (const float*)d_in[7];
    const float* Bv   = (const float*)d_in[8];
    const float* Cm   = (const float*)d_in[9];
    const float* bA   = (const float*)d_in[10];
    const float* bC   = (const float*)d_in[11];
    const float* gw   = (const float*)d_in[12];
    const float* gbia = (const float*)d_in[13];
    const float* pw   = (const float*)d_in[14];
    const float* pb   = (const float*)d_in[15];
    const float* ow   = (const float*)d_in[16];
    const float* ob   = (const float*)d_in[17];

    char* ws = (char*)d_ws;
    float*          u  = (float*)(ws + 0);                   // 4 MB
    unsigned short* Hs = (unsigned short*)(ws + 4194304);    // 2 MB
    unsigned short* hb = (unsigned short*)(ws + 14680064);   // 8 MB (bf16 residual)
    unsigned short* wb = (unsigned short*)(ws + 25165824);   // 2 MB
    unsigned short* xnb = (unsigned short*)(ws + 44040192);  // 8 MB
    unsigned short* gB  = (unsigned short*)(ws + 52428800);  // 8 MB

    char* sc = (char*)d_out;   // small scratch; fully overwritten by final GEMM
    float* Apow  = (float*)(sc + 0);          // 64 KB: [4][64][64] (A^32)
    float* Slast = (float*)(sc + 65536);      // 128 KB: [64*8][64]
    int*   flag  = (int*)(sc + 196608);       // 16 B

    const unsigned short* w_in = wb + 0;
    const unsigned short* w_ip = wb + 196608;
    const unsigned short* w_g  = wb + 262144;
    const unsigned short* w_p  = wb + 524288;
    const unsigned short* w_c  = wb + 786432;
    const unsigned short* w_o  = wb + 851968;

    hipMemsetAsync(flag, 0, 16, stream);
    cvt_w_k<<<4096, 256, 0, stream>>>(inw, ipw, gw, pw, Cm, ow, wb);
    matpow_k<<<4, 256, 0, stream>>>(Amat, Apow);

    in_ln_k<<<512, 256, 0, stream>>>(x, w_in, inb, lng, lnb, hb, xnb);
    for (int i = 0; i < 4; i++) {
        gateip_k<<<dim3(128, 5), 256, 0, stream>>>(xnb, w_g + i * 65536, w_ip + i * 16384,
                                                   gbia + i * HD, ipb + i * SD,
                                                   Bv + i * SD, bA + i * SD, gB, u);
        scan_chunk_k<<<512, 64, 0, stream>>>(Amat + i * 4096, u, Slast);
        replay_k<<<512, 64, 0, stream>>>(Amat + i * 4096, Apow + i * 4096, u, Slast, Hs, flag + i);
        scan_seq_k<<<8, 64, 0, stream>>>(Amat + i * 4096, u, Hs, flag + i);
        if (i < 3)
            post3_k<false><<<512, 256, 0, stream>>>(Hs, w_c + i * 16384, bC + i * HD,
                                                    w_p + i * 65536, pb + i * HD, gB, xnb, hb,
                                                    lng + (i + 1) * HD, lnb + (i + 1) * HD);
        else
            post3_k<true><<<512, 256, 0, stream>>>(Hs, w_c + i * 16384, bC + i * HD,
                                                   w_p + i * 65536, pb + i * HD, gB, xnb, hb,
                                                   lng, lnb);
    }
    gemm_k<DOUT><<<dim3(128, 12), 256, 0, stream>>>(hb, w_o, ob, (float*)d_out);
}